// Round 5
// baseline (2702.150 us; speedup 1.0000x reference)
//
#include <hip/hip_runtime.h>
#include <hip/hip_bf16.h>
#include <cstdint>

constexpr int NB = 2, NS = 1024, ND = 1024, NH = 16, NL = 6, NV = 32000, NF = 4096, NDH = 64;

using bf16 = __hip_bfloat16;
typedef __bf16 bf16x8 __attribute__((ext_vector_type(8)));
typedef float f32x4 __attribute__((ext_vector_type(4)));

#define AS1(p) ((const __attribute__((address_space(1))) void*)(p))
#define AS3(p) ((__attribute__((address_space(3))) void*)(p))

__device__ __forceinline__ float gelu_f(float x) {
  // tanh-approx GELU via sigmoid: gelu(x) = x * sigmoid(2*0.79788456*(x+0.044715x^3))
  float z = 1.5957691216057308f * (x + 0.044715f * x * x * x);
  return x / (1.f + __expf(-z));
}

// ---------------- GEMM: C[M,N] = A[M,K] @ Bt[N,K]^T (+bias) ----------------
// EP: 0=f32 out, 1=bf16 out, 2=bf16 out w/ GELU, 3=f32 scatter-add rel-skew
// CZ: 0=none, 1=skip if n0>m0+BM-1 (causal QK), 2=kEnd=min(K,m0+BM) (causal PV),
//     3=skip tile fully left of rel-diagonal (QE)
// SWZ: 1 = M-major tile order + bijective XCD-chunk swizzle (B-panel L2 reuse)
template<int BN, int EP, int CZ, bool HASBIAS, int SWZ>
__global__ __launch_bounds__(256)
void gemm_bt(const bf16* __restrict__ A, const bf16* __restrict__ Bt,
             void* __restrict__ Cv, const float* __restrict__ bias,
             int M, int N, int K, int lda, int ldb, int ldc, int ZH,
             long sAb, long sAh, long sBb, long sBh, long sCb, long sCh, long sBias)
{
  constexpr int BM = 128, BK = 32;
  constexpr int WGN = (BN == 128) ? 2 : 1;
  constexpr int FM  = (BM / (4 / WGN)) / 16;
  constexpr int FN  = (BN / WGN) / 16;

  const int z  = blockIdx.z;
  const int zb = z / ZH, zh = z % ZH;
  const bf16* Ab = A + (long)zb * sAb + (long)zh * sAh;
  const bf16* Bb = Bt + (long)zb * sBb + (long)zh * sBh;

  int m0, n0;
  if constexpr (SWZ == 1) {
    // nwg multiple of 8 in all our launches -> xcd*q + idx is bijective (m204)
    const int nM = gridDim.y, nN = gridDim.x;
    const int nwg = nM * nN;
    const int bid = blockIdx.y * nN + blockIdx.x;
    const int qq = nwg >> 3;
    const int xcd = bid & 7, idx = bid >> 3;
    const int wg = xcd * qq + idx;
    m0 = (wg % nM) * BM;   // M fastest: consecutive blocks share the B-panel
    n0 = (wg / nM) * BN;
  } else {
    m0 = blockIdx.y * BM;
    n0 = blockIdx.x * BN;
  }

  if constexpr (CZ == 1) { if (n0 > m0 + BM - 1) return; }
  if constexpr (CZ == 3) { if (m0 + n0 + BM + BN - 2 < NS - 1) return; }

  int kEnd = K;
  if constexpr (CZ == 2) kEnd = (K < m0 + BM) ? K : (m0 + BM);

  __shared__ bf16 Asm[BM * BK];
  __shared__ bf16 Bsm[BN * BK];

  const int tid  = threadIdx.x;
  const int lane = tid & 63;
  const int wid  = tid >> 6;
  const int wm = (wid / WGN) * (FM * 16);
  const int wn = (wid % WGN) * (FN * 16);
  const int l15 = lane & 15;
  const int lk8 = (lane >> 4) * 8;

  f32x4 acc[FM][FN] = {};

  // staging: thread t covers row t/4, col (t%4)*8; linear LDS = t*16 bytes
  const int srow = tid >> 2;
  const int scol = (tid & 3) * 8;
  const bf16* gA = Ab + (long)(m0 + srow) * lda + scol;
  const bf16* gB = Bb + (long)(n0 + srow) * ldb + scol;
  bf16* ldsA = Asm + wid * 512;   // wave-uniform base; HW scatters lane*16B
  bf16* ldsB = Bsm + wid * 512;

  for (int k0 = 0; k0 < kEnd; k0 += BK) {
    __builtin_amdgcn_global_load_lds(AS1(gA + k0), AS3(ldsA), 16, 0, 0);
    __builtin_amdgcn_global_load_lds(AS1(gA + 64l * lda + k0), AS3(ldsA + 2048), 16, 0, 0);
    __builtin_amdgcn_global_load_lds(AS1(gB + k0), AS3(ldsB), 16, 0, 0);
    if constexpr (BN == 128)
      __builtin_amdgcn_global_load_lds(AS1(gB + 64l * ldb + k0), AS3(ldsB + 2048), 16, 0, 0);
    asm volatile("s_waitcnt vmcnt(0)" ::: "memory");
    __syncthreads();

    bf16x8 af[FM], bfr[FN];
    #pragma unroll
    for (int i = 0; i < FM; ++i)
      af[i] = *reinterpret_cast<const bf16x8*>(&Asm[(wm + i * 16 + l15) * BK + lk8]);
    #pragma unroll
    for (int j = 0; j < FN; ++j)
      bfr[j] = *reinterpret_cast<const bf16x8*>(&Bsm[(wn + j * 16 + l15) * BK + lk8]);
    #pragma unroll
    for (int i = 0; i < FM; ++i)
      #pragma unroll
      for (int j = 0; j < FN; ++j)
        acc[i][j] = __builtin_amdgcn_mfma_f32_16x16x32_bf16(af[i], bfr[j], acc[i][j], 0, 0, 0);
    __syncthreads();
  }

  const int rq = (lane >> 4) * 4;
  if constexpr (EP == 3) {
    // scatter-add: scores[q, q+m-(S-1)] += QE[q, m]
    float* C = (float*)Cv + (long)zb * sCb + (long)zh * sCh;
    #pragma unroll
    for (int i = 0; i < FM; ++i) {
      const int r0 = m0 + wm + i * 16 + rq;
      #pragma unroll
      for (int j = 0; j < FN; ++j) {
        const int cm = n0 + wn + j * 16 + l15;
        #pragma unroll
        for (int e = 0; e < 4; ++e) {
          const int tgt = (r0 + e) + cm - (NS - 1);
          if (tgt >= 0) C[(long)(r0 + e) * ldc + tgt] += acc[i][j][e];
        }
      }
    }
  } else {
    const long cb = (long)zb * sCb + (long)zh * sCh;
    #pragma unroll
    for (int i = 0; i < FM; ++i) {
      const int r0 = m0 + wm + i * 16 + rq;
      #pragma unroll
      for (int j = 0; j < FN; ++j) {
        const int c = n0 + wn + j * 16 + l15;
        float bv = 0.f;
        if constexpr (HASBIAS) bv = bias[(long)zb * sBias + c];
        #pragma unroll
        for (int e = 0; e < 4; ++e) {
          float v = acc[i][j][e] + bv;
          if constexpr (EP == 2) v = gelu_f(v);
          const long idx = cb + (long)(r0 + e) * ldc + c;
          if constexpr (EP == 0) ((float*)Cv)[idx] = v;
          else                   ((bf16*)Cv)[idx] = __float2bfloat16(v);
        }
      }
    }
  }
}

// ------------- transpose+convert: in f32 (R x C) -> out bf16 (C x R) -------------
__global__ void transpose_f32_bf16(const float* __restrict__ in, bf16* __restrict__ out,
                                   int R, int C, long inZ, long outZ) {
  __shared__ float t[32][33];
  const float* ip = in + (long)blockIdx.z * inZ;
  bf16* op = out + (long)blockIdx.z * outZ;
  const int c0 = blockIdx.x * 32, r0 = blockIdx.y * 32;
  const int tx = threadIdx.x, ty = threadIdx.y;
  #pragma unroll
  for (int i = 0; i < 4; ++i)
    t[ty * 4 + i][tx] = ip[(long)(r0 + ty * 4 + i) * C + c0 + tx];
  __syncthreads();
  #pragma unroll
  for (int i = 0; i < 4; ++i)
    op[(long)(c0 + ty * 4 + i) * R + r0 + tx] = __float2bfloat16(t[tx][ty * 4 + i]);
}

// v (B,S,D) -> vt (B,H,Dh,S)
__global__ void transpose_v_k(const bf16* __restrict__ v, bf16* __restrict__ vt) {
  __shared__ bf16 t[32][33];
  const int z = blockIdx.z, b = z >> 4, h = z & 15;
  const bf16* ip = v + (long)b * NS * ND + h * 64;
  bf16* op = vt + (long)z * 64 * NS;
  const int s0 = blockIdx.x * 32, d0 = blockIdx.y * 32;
  const int tx = threadIdx.x, ty = threadIdx.y;
  #pragma unroll
  for (int i = 0; i < 4; ++i)
    t[ty * 4 + i][tx] = ip[(long)(s0 + ty * 4 + i) * ND + d0 + tx];
  __syncthreads();
  #pragma unroll
  for (int i = 0; i < 4; ++i)
    op[(long)(d0 + ty * 4 + i) * NS + s0 + tx] = t[tx][ty * 4 + i];
}

__global__ void cvt_bf16_k(const float* __restrict__ in, bf16* __restrict__ out, int n) {
  int i = blockIdx.x * 256 + threadIdx.x;
  if (i < n) out[i] = __float2bfloat16(in[i]);
}

// pack bq,bk,bv (each L x D) -> out [L][3][D]
__global__ void pack3_k(const float* __restrict__ a, const float* __restrict__ b,
                        const float* __restrict__ c, float* __restrict__ out) {
  int i = blockIdx.x * 256 + threadIdx.x;
  if (i >= NL * 3 * ND) return;
  int d = i % ND, r = (i / ND) % 3, l = i / (3 * ND);
  const float* src = (r == 0) ? a : ((r == 1) ? b : c);
  out[i] = src[l * ND + d];
}

__global__ void embed_k(const int* __restrict__ tok, const float* __restrict__ emb,
                        float* __restrict__ x, bf16* __restrict__ xb) {
  const int row = blockIdx.x;
  const int t = tok[row];
  const float4 val = ((const float4*)(emb + (long)t * ND))[threadIdx.x];
  ((float4*)(x + (long)row * ND))[threadIdx.x] = val;
  bf16* xp = xb + (long)row * ND + threadIdx.x * 4;
  xp[0] = __float2bfloat16(val.x); xp[1] = __float2bfloat16(val.y);
  xp[2] = __float2bfloat16(val.z); xp[3] = __float2bfloat16(val.w);
}

// causal softmax, one wave per row; writes bf16 P in place over the f32 row.
// Loads only k <= q (causal); writes zeros up to the 128-tile boundary
// (PV consumes k < (q|127)+1), leaves the rest stale (never read).
__global__ void softmax_k(float* __restrict__ sc) {
  const int row = blockIdx.x * 4 + (threadIdx.x >> 6);
  const int lane = threadIdx.x & 63;
  const int q = row & (NS - 1);
  const int iq = q >> 6;          // last 64-block containing valid k
  const int iw = iq | 1;          // write-zero up to PV's kEnd tile boundary
  float* p = sc + (long)row * NS;
  float v[16];
  float mx = -1e30f;
  #pragma unroll
  for (int i = 0; i < 16; ++i) {
    if (i > iq) break;            // wave-uniform early exit; v[] stays static-indexed
    const int idx = i * 64 + lane;
    const float t = p[idx];
    v[i] = (idx <= q) ? t * 0.125f : -1e30f;   // *1/sqrt(64); mask
    mx = fmaxf(mx, v[i]);
  }
  #pragma unroll
  for (int o = 32; o; o >>= 1) mx = fmaxf(mx, __shfl_xor(mx, o));
  float sum = 0.f;
  #pragma unroll
  for (int i = 0; i < 16; ++i) {
    if (i > iq) break;
    const int idx = i * 64 + lane;
    const float e = (idx <= q) ? __expf(v[i] - mx) : 0.f;
    v[i] = e; sum += e;
  }
  #pragma unroll
  for (int o = 32; o; o >>= 1) sum += __shfl_xor(sum, o);
  const float r = 1.f / sum;
  bf16* ob = (bf16*)p;
  #pragma unroll
  for (int i = 0; i < 16; ++i) {
    if (i > iw) break;
    const float val = (i <= iq) ? v[i] * r : 0.f;
    ob[i * 64 + lane] = __float2bfloat16(val);
  }
}

// x = LN(x + g) * s + b (in place on x), also emit xb = bf16(x)
__global__ void resid_ln_k(float* __restrict__ x, const float* __restrict__ g,
                           const float* __restrict__ s, const float* __restrict__ b,
                           bf16* __restrict__ xb) {
  const int row = blockIdx.x, tid = threadIdx.x;
  const float4 xv = ((const float4*)(x + (long)row * ND))[tid];
  const float4 gv = ((const float4*)(g + (long)row * ND))[tid];
  float h0 = xv.x + gv.x, h1 = xv.y + gv.y, h2 = xv.z + gv.z, h3 = xv.w + gv.w;
  float ls = h0 + h1 + h2 + h3;
  __shared__ float red[8];
  #pragma unroll
  for (int o = 32; o; o >>= 1) ls += __shfl_xor(ls, o);
  const int lane = tid & 63, wid = tid >> 6;
  if (lane == 0) red[wid] = ls;
  __syncthreads();
  const float mu = (red[0] + red[1] + red[2] + red[3]) * (1.f / ND);
  const float d0 = h0 - mu, d1 = h1 - mu, d2 = h2 - mu, d3 = h3 - mu;
  float lv = d0 * d0 + d1 * d1 + d2 * d2 + d3 * d3;
  #pragma unroll
  for (int o = 32; o; o >>= 1) lv += __shfl_xor(lv, o);
  if (lane == 0) red[4 + wid] = lv;
  __syncthreads();
  const float rs = rsqrtf((red[4] + red[5] + red[6] + red[7]) * (1.f / ND) + 1e-5f);
  const float4 sv = ((const float4*)s)[tid];
  const float4 bv = ((const float4*)b)[tid];
  const float y0 = d0 * rs * sv.x + bv.x, y1 = d1 * rs * sv.y + bv.y;
  const float y2 = d2 * rs * sv.z + bv.z, y3 = d3 * rs * sv.w + bv.w;
  ((float4*)(x + (long)row * ND))[tid] = make_float4(y0, y1, y2, y3);
  bf16* xp = xb + (long)row * ND + tid * 4;
  xp[0] = __float2bfloat16(y0); xp[1] = __float2bfloat16(y1);
  xp[2] = __float2bfloat16(y2); xp[3] = __float2bfloat16(y3);
}

extern "C" void kernel_launch(void* const* d_in, const int* in_sizes, int n_in,
                              void* d_out, int out_size, void* d_ws, size_t ws_size,
                              hipStream_t stream) {
  const int*   tokens = (const int*)d_in[0];
  const float* emb  = (const float*)d_in[1];
  const float* Wq   = (const float*)d_in[2];
  const float* bq   = (const float*)d_in[3];
  const float* Wk   = (const float*)d_in[4];
  const float* bk   = (const float*)d_in[5];
  const float* Wv   = (const float*)d_in[6];
  const float* bv   = (const float*)d_in[7];
  const float* Wo   = (const float*)d_in[8];
  const float* bo   = (const float*)d_in[9];
  const float* rpe  = (const float*)d_in[10];
  const float* ln1s = (const float*)d_in[11];
  const float* ln1b = (const float*)d_in[12];
  const float* ln2s = (const float*)d_in[13];
  const float* ln2b = (const float*)d_in[14];
  const float* W1   = (const float*)d_in[15];
  const float* b1   = (const float*)d_in[16];
  const float* W2   = (const float*)d_in[17];
  const float* b2   = (const float*)d_in[18];
  const float* Wout = (const float*)d_in[19];
  const float* bout = (const float*)d_in[20];
  float* out = (float*)d_out;

  char* wsb = (char*)d_ws;
  size_t off = 0;
  auto take = [&](size_t bytes) -> void* {
    void* r = wsb + off;
    off = (off + bytes + 255) & ~(size_t)255;
    return r;
  };
  bf16*  wqkvT = (bf16*)take((size_t)NL * 3 * ND * ND * 2);   // [L][3][N=D][K=D]
  bf16*  woT   = (bf16*)take((size_t)NL * ND * ND * 2);
  bf16*  w1T   = (bf16*)take((size_t)NL * NF * ND * 2);       // [L][N=F][K=D]
  bf16*  w2T   = (bf16*)take((size_t)NL * ND * NF * 2);       // [L][N=D][K=F]
  bf16*  woutT = (bf16*)take((size_t)NV * ND * 2);            // [N=V][K=D]
  bf16*  rpeb  = (bf16*)take((size_t)NL * NS * NDH * 2);
  float* qkvb  = (float*)take((size_t)NL * 3 * ND * 4);
  float* x     = (float*)take((size_t)NB * NS * ND * 4);
  bf16*  xb    = (bf16*)take((size_t)NB * NS * ND * 2);
  bf16*  qkv   = (bf16*)take((size_t)3 * NB * NS * ND * 2);   // [3][B][S][D]
  bf16*  vt    = (bf16*)take((size_t)NB * NS * ND * 2);       // [B][H][Dh][S]
  bf16*  ob    = (bf16*)take((size_t)NB * NS * ND * 2);
  float* g     = (float*)take((size_t)NB * NS * NF * 4);
  bf16*  hbuf  = (bf16*)take((size_t)NB * NS * NF * 2);
  float* sc    = (float*)take((size_t)NB * NH * NS * NS * 4);
  (void)in_sizes; (void)n_in; (void)out_size; (void)ws_size;

  const dim3 tb(32, 8);
  // weight transposes (f32 -> bf16, B^T layout)
  transpose_f32_bf16<<<dim3(ND/32, ND/32, NL), tb, 0, stream>>>(Wq, wqkvT,                      ND, ND, (long)ND*ND, (long)3*ND*ND);
  transpose_f32_bf16<<<dim3(ND/32, ND/32, NL), tb, 0, stream>>>(Wk, wqkvT + (size_t)ND*ND,      ND, ND, (long)ND*ND, (long)3*ND*ND);
  transpose_f32_bf16<<<dim3(ND/32, ND/32, NL), tb, 0, stream>>>(Wv, wqkvT + (size_t)2*ND*ND,    ND, ND, (long)ND*ND, (long)3*ND*ND);
  transpose_f32_bf16<<<dim3(ND/32, ND/32, NL), tb, 0, stream>>>(Wo, woT,                        ND, ND, (long)ND*ND, (long)ND*ND);
  transpose_f32_bf16<<<dim3(NF/32, ND/32, NL), tb, 0, stream>>>(W1, w1T,                        ND, NF, (long)ND*NF, (long)NF*ND);
  transpose_f32_bf16<<<dim3(ND/32, NF/32, NL), tb, 0, stream>>>(W2, w2T,                        NF, ND, (long)NF*ND, (long)ND*NF);
  transpose_f32_bf16<<<dim3(NV/32, ND/32, 1),  tb, 0, stream>>>(Wout, woutT,                    ND, NV, 0, 0);
  cvt_bf16_k<<<(NL*NS*NDH + 255)/256, 256, 0, stream>>>(rpe, rpeb, NL*NS*NDH);
  pack3_k<<<(NL*3*ND + 255)/256, 256, 0, stream>>>(bq, bk, bv, qkvb);
  embed_k<<<NB*NS, 256, 0, stream>>>(tokens, emb, x, xb);

  for (int l = 0; l < NL; ++l) {
    // QKV projections (batched z=0,1,2), bf16 out + bias
    gemm_bt<128, 1, 0, true, 1><<<dim3(ND/128, NB*NS/128, 3), 256, 0, stream>>>(
        xb, wqkvT + (size_t)l*3*ND*ND, qkv, qkvb + (size_t)l*3*ND,
        NB*NS, ND, ND, ND, ND, ND, 1,
        0, 0, (long)ND*ND, 0, (long)NB*NS*ND, 0, ND);
    transpose_v_k<<<dim3(NS/32, 2, NB*NH), tb, 0, stream>>>(qkv + (size_t)2*NB*NS*ND, vt);
    // QK^T -> scores (f32), causal tile skip
    gemm_bt<128, 0, 1, false, 0><<<dim3(NS/128, NS/128, NB*NH), 256, 0, stream>>>(
        qkv, qkv + (size_t)NB*NS*ND, sc, nullptr,
        NS, NS, NDH, ND, ND, NS, NH,
        (long)NS*ND, 64, (long)NS*ND, 64, (long)NH*NS*NS, (long)NS*NS, 0);
    // Q @ E^T, skew-scatter-add into scores
    gemm_bt<128, 3, 3, false, 0><<<dim3(NS/128, NS/128, NB*NH), 256, 0, stream>>>(
        qkv, rpeb + (size_t)l*NS*NDH, sc, nullptr,
        NS, NS, NDH, ND, NDH, NS, NH,
        (long)NS*ND, 64, 0, 0, (long)NH*NS*NS, (long)NS*NS, 0);
    softmax_k<<<NB*NH*NS/4, 256, 0, stream>>>(sc);
    // P @ V -> attn out (bf16, scattered into (B,S,D) by head), causal kEnd
    gemm_bt<64, 1, 2, false, 0><<<dim3(1, NS/128, NB*NH), 256, 0, stream>>>(
        (const bf16*)sc, vt, ob, nullptr,
        NS, NDH, NS, 2*NS, NS, ND, NH,
        (long)NH*NS*NS*2, (long)NS*NS*2, (long)NH*NDH*NS, (long)NDH*NS, (long)NS*ND, 64, 0);
    // O projection -> g (f32) + bias
    gemm_bt<128, 0, 0, true, 1><<<dim3(ND/128, NB*NS/128, 1), 256, 0, stream>>>(
        ob, woT + (size_t)l*ND*ND, g, bo + (size_t)l*ND,
        NB*NS, ND, ND, ND, ND, ND, 1, 0,0, 0,0, 0,0, 0);
    resid_ln_k<<<NB*NS, 256, 0, stream>>>(x, g, ln1s + (size_t)l*ND, ln1b + (size_t)l*ND, xb);
    // FFN1: bias + GELU fused, bf16 out
    gemm_bt<128, 2, 0, true, 1><<<dim3(NF/128, NB*NS/128, 1), 256, 0, stream>>>(
        xb, w1T + (size_t)l*NF*ND, hbuf, b1 + (size_t)l*NF,
        NB*NS, NF, ND, ND, ND, NF, 1, 0,0, 0,0, 0,0, 0);
    // FFN2 -> g (f32) + bias
    gemm_bt<128, 0, 0, true, 1><<<dim3(ND/128, NB*NS/128, 1), 256, 0, stream>>>(
        hbuf, w2T + (size_t)l*ND*NF, g, b2 + (size_t)l*ND,
        NB*NS, ND, NF, NF, NF, ND, 1, 0,0, 0,0, 0,0, 0);
    resid_ln_k<<<NB*NS, 256, 0, stream>>>(x, g, ln2s + (size_t)l*ND, ln2b + (size_t)l*ND, xb);
  }
  // final vocab projection (f32 out + bias)
  gemm_bt<128, 0, 0, true, 1><<<dim3(NV/128, NB*NS/128, 1), 256, 0, stream>>>(
      xb, woutT, out, bout,
      NB*NS, NV, ND, ND, ND, NV, 1, 0,0, 0,0, 0,0, 0);
}

// Round 6
// 2646.122 us; speedup vs baseline: 1.0212x; 1.0212x over previous
//
#include <hip/hip_runtime.h>
#include <hip/hip_bf16.h>
#include <cstdint>

constexpr int NB = 2, NS = 1024, ND = 1024, NH = 16, NL = 6, NV = 32000, NF = 4096, NDH = 64;

using bf16 = __hip_bfloat16;
typedef __bf16 bf16x8 __attribute__((ext_vector_type(8)));
typedef float f32x4 __attribute__((ext_vector_type(4)));

#define AS1(p) ((const __attribute__((address_space(1))) void*)(p))
#define AS3(p) ((__attribute__((address_space(3))) void*)(p))

__device__ __forceinline__ float gelu_f(float x) {
  // tanh-approx GELU via sigmoid: gelu(x) = x * sigmoid(2*0.79788456*(x+0.044715x^3))
  float z = 1.5957691216057308f * (x + 0.044715f * x * x * x);
  return x / (1.f + __expf(-z));
}

// ================= 256x256 deep-pipelined GEMM (T2+T3+T4+T5) =================
// C[M,N] = A[M,K] @ Bt[N,K]^T (+bias). EP: 0=f32 out, 2=bf16 out w/ GELU.
// 8 waves (512 thr), BK=32, 4-deep LDS circular buffer (128 KiB), counted
// vmcnt(8) steady state (never 0 in main loop), raw s_barrier (no drain),
// T2 swizzle: LDS byte ^= ((byte>>9)&1)<<5 (pre-swizzled global source +
// swizzled ds_read — both sides, rule #21). Requires M%256==0, N%256==0,
// K%32==0, K/32>=4, grid (N/256, M/256) with nwg%8==0.
template<int EP, bool HASBIAS>
__global__ __launch_bounds__(512)
void gemm256_bt(const bf16* __restrict__ A, const bf16* __restrict__ Bt,
                void* __restrict__ Cv, const float* __restrict__ bias,
                int K, int lda, int ldb, int ldc)
{
  // XCD-chunk + M-major swizzle (nwg % 8 == 0): consecutive blocks on one
  // XCD walk M fastest -> share the 256-row B panel in that XCD's L2.
  const int nM = gridDim.y, nN = gridDim.x;
  const int nwg = nM * nN;
  const int bid = blockIdx.y * nN + blockIdx.x;
  const int qq = nwg >> 3;
  const int wg = (bid & 7) * qq + (bid >> 3);
  const int m0 = (wg % nM) * 256;
  const int n0 = (wg / nM) * 256;

  __shared__ char lds[131072];   // [buf:4][32768] ; within buf: A 16KB, B 16KB

  const int tid  = threadIdx.x;
  const int lane = tid & 63;
  const int wid  = tid >> 6;
  const int wm = (wid >> 2) * 128;   // 2 M-waves x 4 N-waves
  const int wn = (wid & 3) * 64;
  const int l15 = lane & 15;

  // ds_read k-offset bytes within a row, T2-swizzled: key = row bit3 = l15 bit3
  const int rdk = ((lane >> 4) * 16) ^ ((l15 >> 3) << 5);

  // staging source coords (pre-swizzled so linear global_load_lds dest +
  // swizzled read agree). thread covers 16 B at tile byte p = tid*16:
  // row = tid>>2, colel = (tid&3)*8 ^ (bit9(p))*16 ; bit9(p) = (lane>>5)&1.
  const int srow = wid * 16 + (lane >> 2);                 // 0..127
  const int scol = ((lane & 3) * 8) ^ (((lane >> 5) & 1) << 4);
  const bf16* gA = A  + (long)(m0 + srow) * lda + scol;
  const bf16* gB = Bt + (long)(n0 + srow) * ldb + scol;
  const long a128 = (long)128 * lda, b128 = (long)128 * ldb;
  char* ldsW = lds + wid * 1024;   // per-wave chunk base (lane*16 appended by HW)

  f32x4 acc[8][4] = {};
  const int NT = K >> 5;

#define STG(t_) do {                                                                   \
    const int b_ = ((t_) & 3) * 32768; const long ko_ = (long)(t_) * 32;               \
    __builtin_amdgcn_global_load_lds(AS1(gA + ko_),        AS3(ldsW + b_),          16, 0, 0); \
    __builtin_amdgcn_global_load_lds(AS1(gA + ko_ + a128), AS3(ldsW + b_ + 8192),   16, 0, 0); \
    __builtin_amdgcn_global_load_lds(AS1(gB + ko_),        AS3(ldsW + b_ + 16384),  16, 0, 0); \
    __builtin_amdgcn_global_load_lds(AS1(gB + ko_ + b128), AS3(ldsW + b_ + 24576),  16, 0, 0); \
  } while (0)

  // Per-tile step. vmcnt(vm_) ensures tile t_ fully landed (per-wave count,
  // then barrier makes it collective). Stage of t_+3 lands into buf[(t_-1)&3],
  // whose readers all passed this barrier after their lgkmcnt-complete reads.
#define TILE(t_, vm_) do {                                                             \
    asm volatile("s_waitcnt vmcnt(" #vm_ ")" ::: "memory");                            \
    __builtin_amdgcn_s_barrier();                                                      \
    asm volatile("" ::: "memory");                                                     \
    if ((t_) + 3 < NT) STG((t_) + 3);                                                  \
    const char* la_ = lds + (((t_) & 3) * 32768);                                      \
    const char* lb_ = la_ + 16384;                                                     \
    bf16x8 bf_[4], af_[8];                                                             \
    _Pragma("unroll") for (int j_ = 0; j_ < 4; ++j_)                                   \
      bf_[j_] = *(const bf16x8*)(lb_ + (wn + j_ * 16 + l15) * 64 + rdk);               \
    _Pragma("unroll") for (int i_ = 0; i_ < 8; ++i_)                                   \
      af_[i_] = *(const bf16x8*)(la_ + (wm + i_ * 16 + l15) * 64 + rdk);               \
    __builtin_amdgcn_s_setprio(1);                                                     \
    _Pragma("unroll") for (int i_ = 0; i_ < 8; ++i_)                                   \
      _Pragma("unroll") for (int j_ = 0; j_ < 4; ++j_)                                 \
        acc[i_][j_] = __builtin_amdgcn_mfma_f32_16x16x32_bf16(af_[i_], bf_[j_], acc[i_][j_], 0, 0, 0); \
    __builtin_amdgcn_s_setprio(0);                                                     \
  } while (0)

  // prologue: 3 tiles in flight
  STG(0); STG(1); STG(2);
  int t = 0;
  for (; t < NT - 3; ++t) TILE(t, 8);
  TILE(NT - 3, 8);
  TILE(NT - 2, 4);
  TILE(NT - 1, 0);
#undef TILE
#undef STG

  const int rq = (lane >> 4) * 4;
  #pragma unroll
  for (int i = 0; i < 8; ++i) {
    const int r0 = m0 + wm + i * 16 + rq;
    #pragma unroll
    for (int j = 0; j < 4; ++j) {
      const int c = n0 + wn + j * 16 + l15;
      float bv = 0.f;
      if constexpr (HASBIAS) bv = bias[c];
      #pragma unroll
      for (int e = 0; e < 4; ++e) {
        float v = acc[i][j][e] + bv;
        if constexpr (EP == 2) v = gelu_f(v);
        if constexpr (EP == 0) ((float*)Cv)[(long)(r0 + e) * ldc + c] = v;
        else                   ((bf16*)Cv)[(long)(r0 + e) * ldc + c] = __float2bfloat16(v);
      }
    }
  }
}

// ---------------- GEMM: C[M,N] = A[M,K] @ Bt[N,K]^T (+bias) ----------------
// EP: 0=f32 out, 1=bf16 out, 2=bf16 out w/ GELU, 3=f32 scatter-add rel-skew
// CZ: 0=none, 1=skip if n0>m0+BM-1 (causal QK), 2=kEnd=min(K,m0+BM) (causal PV),
//     3=skip tile fully left of rel-diagonal (QE)
// SWZ: 1 = M-major tile order + bijective XCD-chunk swizzle (B-panel L2 reuse)
template<int BN, int EP, int CZ, bool HASBIAS, int SWZ>
__global__ __launch_bounds__(256)
void gemm_bt(const bf16* __restrict__ A, const bf16* __restrict__ Bt,
             void* __restrict__ Cv, const float* __restrict__ bias,
             int M, int N, int K, int lda, int ldb, int ldc, int ZH,
             long sAb, long sAh, long sBb, long sBh, long sCb, long sCh, long sBias)
{
  constexpr int BM = 128, BK = 32;
  constexpr int WGN = (BN == 128) ? 2 : 1;
  constexpr int FM  = (BM / (4 / WGN)) / 16;
  constexpr int FN  = (BN / WGN) / 16;

  const int z  = blockIdx.z;
  const int zb = z / ZH, zh = z % ZH;
  const bf16* Ab = A + (long)zb * sAb + (long)zh * sAh;
  const bf16* Bb = Bt + (long)zb * sBb + (long)zh * sBh;

  int m0, n0;
  if constexpr (SWZ == 1) {
    const int nM = gridDim.y, nN = gridDim.x;
    const int nwg = nM * nN;
    const int bid = blockIdx.y * nN + blockIdx.x;
    const int qq = nwg >> 3;
    const int xcd = bid & 7, idx = bid >> 3;
    const int wg = xcd * qq + idx;
    m0 = (wg % nM) * BM;   // M fastest: consecutive blocks share the B-panel
    n0 = (wg / nM) * BN;
  } else {
    m0 = blockIdx.y * BM;
    n0 = blockIdx.x * BN;
  }

  if constexpr (CZ == 1) { if (n0 > m0 + BM - 1) return; }
  if constexpr (CZ == 3) { if (m0 + n0 + BM + BN - 2 < NS - 1) return; }

  int kEnd = K;
  if constexpr (CZ == 2) kEnd = (K < m0 + BM) ? K : (m0 + BM);

  __shared__ bf16 Asm[BM * BK];
  __shared__ bf16 Bsm[BN * BK];

  const int tid  = threadIdx.x;
  const int lane = tid & 63;
  const int wid  = tid >> 6;
  const int wm = (wid / WGN) * (FM * 16);
  const int wn = (wid % WGN) * (FN * 16);
  const int l15 = lane & 15;
  const int lk8 = (lane >> 4) * 8;

  f32x4 acc[FM][FN] = {};

  // staging: thread t covers row t/4, col (t%4)*8; linear LDS = t*16 bytes
  const int srow = tid >> 2;
  const int scol = (tid & 3) * 8;
  const bf16* gA = Ab + (long)(m0 + srow) * lda + scol;
  const bf16* gB = Bb + (long)(n0 + srow) * ldb + scol;
  bf16* ldsA = Asm + wid * 512;   // wave-uniform base; HW scatters lane*16B
  bf16* ldsB = Bsm + wid * 512;

  for (int k0 = 0; k0 < kEnd; k0 += BK) {
    __builtin_amdgcn_global_load_lds(AS1(gA + k0), AS3(ldsA), 16, 0, 0);
    __builtin_amdgcn_global_load_lds(AS1(gA + 64l * lda + k0), AS3(ldsA + 2048), 16, 0, 0);
    __builtin_amdgcn_global_load_lds(AS1(gB + k0), AS3(ldsB), 16, 0, 0);
    if constexpr (BN == 128)
      __builtin_amdgcn_global_load_lds(AS1(gB + 64l * ldb + k0), AS3(ldsB + 2048), 16, 0, 0);
    asm volatile("s_waitcnt vmcnt(0)" ::: "memory");
    __syncthreads();

    bf16x8 af[FM], bfr[FN];
    #pragma unroll
    for (int i = 0; i < FM; ++i)
      af[i] = *reinterpret_cast<const bf16x8*>(&Asm[(wm + i * 16 + l15) * BK + lk8]);
    #pragma unroll
    for (int j = 0; j < FN; ++j)
      bfr[j] = *reinterpret_cast<const bf16x8*>(&Bsm[(wn + j * 16 + l15) * BK + lk8]);
    #pragma unroll
    for (int i = 0; i < FM; ++i)
      #pragma unroll
      for (int j = 0; j < FN; ++j)
        acc[i][j] = __builtin_amdgcn_mfma_f32_16x16x32_bf16(af[i], bfr[j], acc[i][j], 0, 0, 0);
    __syncthreads();
  }

  const int rq = (lane >> 4) * 4;
  if constexpr (EP == 3) {
    // scatter-add: scores[q, q+m-(S-1)] += QE[q, m]
    float* C = (float*)Cv + (long)zb * sCb + (long)zh * sCh;
    #pragma unroll
    for (int i = 0; i < FM; ++i) {
      const int r0 = m0 + wm + i * 16 + rq;
      #pragma unroll
      for (int j = 0; j < FN; ++j) {
        const int cm = n0 + wn + j * 16 + l15;
        #pragma unroll
        for (int e = 0; e < 4; ++e) {
          const int tgt = (r0 + e) + cm - (NS - 1);
          if (tgt >= 0) C[(long)(r0 + e) * ldc + tgt] += acc[i][j][e];
        }
      }
    }
  } else {
    const long cb = (long)zb * sCb + (long)zh * sCh;
    #pragma unroll
    for (int i = 0; i < FM; ++i) {
      const int r0 = m0 + wm + i * 16 + rq;
      #pragma unroll
      for (int j = 0; j < FN; ++j) {
        const int c = n0 + wn + j * 16 + l15;
        float bv = 0.f;
        if constexpr (HASBIAS) bv = bias[(long)zb * sBias + c];
        #pragma unroll
        for (int e = 0; e < 4; ++e) {
          float v = acc[i][j][e] + bv;
          if constexpr (EP == 2) v = gelu_f(v);
          const long idx = cb + (long)(r0 + e) * ldc + c;
          if constexpr (EP == 0) ((float*)Cv)[idx] = v;
          else                   ((bf16*)Cv)[idx] = __float2bfloat16(v);
        }
      }
    }
  }
}

// ------------- transpose+convert: in f32 (R x C) -> out bf16 (C x R) -------------
__global__ void transpose_f32_bf16(const float* __restrict__ in, bf16* __restrict__ out,
                                   int R, int C, long inZ, long outZ) {
  __shared__ float t[32][33];
  const float* ip = in + (long)blockIdx.z * inZ;
  bf16* op = out + (long)blockIdx.z * outZ;
  const int c0 = blockIdx.x * 32, r0 = blockIdx.y * 32;
  const int tx = threadIdx.x, ty = threadIdx.y;
  #pragma unroll
  for (int i = 0; i < 4; ++i)
    t[ty * 4 + i][tx] = ip[(long)(r0 + ty * 4 + i) * C + c0 + tx];
  __syncthreads();
  #pragma unroll
  for (int i = 0; i < 4; ++i)
    op[(long)(c0 + ty * 4 + i) * R + r0 + tx] = __float2bfloat16(t[tx][ty * 4 + i]);
}

// v (B,S,D) -> vt (B,H,Dh,S)
__global__ void transpose_v_k(const bf16* __restrict__ v, bf16* __restrict__ vt) {
  __shared__ bf16 t[32][33];
  const int z = blockIdx.z, b = z >> 4, h = z & 15;
  const bf16* ip = v + (long)b * NS * ND + h * 64;
  bf16* op = vt + (long)z * 64 * NS;
  const int s0 = blockIdx.x * 32, d0 = blockIdx.y * 32;
  const int tx = threadIdx.x, ty = threadIdx.y;
  #pragma unroll
  for (int i = 0; i < 4; ++i)
    t[ty * 4 + i][tx] = ip[(long)(s0 + ty * 4 + i) * ND + d0 + tx];
  __syncthreads();
  #pragma unroll
  for (int i = 0; i < 4; ++i)
    op[(long)(d0 + ty * 4 + i) * NS + s0 + tx] = t[tx][ty * 4 + i];
}

__global__ void cvt_bf16_k(const float* __restrict__ in, bf16* __restrict__ out, int n) {
  int i = blockIdx.x * 256 + threadIdx.x;
  if (i < n) out[i] = __float2bfloat16(in[i]);
}

// pack bq,bk,bv (each L x D) -> out [L][3][D]
__global__ void pack3_k(const float* __restrict__ a, const float* __restrict__ b,
                        const float* __restrict__ c, float* __restrict__ out) {
  int i = blockIdx.x * 256 + threadIdx.x;
  if (i >= NL * 3 * ND) return;
  int d = i % ND, r = (i / ND) % 3, l = i / (3 * ND);
  const float* src = (r == 0) ? a : ((r == 1) ? b : c);
  out[i] = src[l * ND + d];
}

__global__ void embed_k(const int* __restrict__ tok, const float* __restrict__ emb,
                        float* __restrict__ x, bf16* __restrict__ xb) {
  const int row = blockIdx.x;
  const int t = tok[row];
  const float4 val = ((const float4*)(emb + (long)t * ND))[threadIdx.x];
  ((float4*)(x + (long)row * ND))[threadIdx.x] = val;
  bf16* xp = xb + (long)row * ND + threadIdx.x * 4;
  xp[0] = __float2bfloat16(val.x); xp[1] = __float2bfloat16(val.y);
  xp[2] = __float2bfloat16(val.z); xp[3] = __float2bfloat16(val.w);
}

// causal softmax, one wave per row; writes bf16 P in place over the f32 row.
// Loads only k <= q (causal); writes zeros up to the 128-tile boundary
// (PV consumes k < (q|127)+1), leaves the rest stale (never read).
__global__ void softmax_k(float* __restrict__ sc) {
  const int row = blockIdx.x * 4 + (threadIdx.x >> 6);
  const int lane = threadIdx.x & 63;
  const int q = row & (NS - 1);
  const int iq = q >> 6;          // last 64-block containing valid k
  const int iw = iq | 1;          // write-zero up to PV's kEnd tile boundary
  float* p = sc + (long)row * NS;
  float v[16];
  float mx = -1e30f;
  #pragma unroll
  for (int i = 0; i < 16; ++i) {
    if (i > iq) break;            // wave-uniform early exit; v[] stays static-indexed
    const int idx = i * 64 + lane;
    const float t = p[idx];
    v[i] = (idx <= q) ? t * 0.125f : -1e30f;   // *1/sqrt(64); mask
    mx = fmaxf(mx, v[i]);
  }
  #pragma unroll
  for (int o = 32; o; o >>= 1) mx = fmaxf(mx, __shfl_xor(mx, o));
  float sum = 0.f;
  #pragma unroll
  for (int i = 0; i < 16; ++i) {
    if (i > iq) break;
    const int idx = i * 64 + lane;
    const float e = (idx <= q) ? __expf(v[i] - mx) : 0.f;
    v[i] = e; sum += e;
  }
  #pragma unroll
  for (int o = 32; o; o >>= 1) sum += __shfl_xor(sum, o);
  const float r = 1.f / sum;
  bf16* ob = (bf16*)p;
  #pragma unroll
  for (int i = 0; i < 16; ++i) {
    if (i > iw) break;
    const float val = (i <= iq) ? v[i] * r : 0.f;
    ob[i * 64 + lane] = __float2bfloat16(val);
  }
}

// x = LN(x + g) * s + b (in place on x), also emit xb = bf16(x)
__global__ void resid_ln_k(float* __restrict__ x, const float* __restrict__ g,
                           const float* __restrict__ s, const float* __restrict__ b,
                           bf16* __restrict__ xb) {
  const int row = blockIdx.x, tid = threadIdx.x;
  const float4 xv = ((const float4*)(x + (long)row * ND))[tid];
  const float4 gv = ((const float4*)(g + (long)row * ND))[tid];
  float h0 = xv.x + gv.x, h1 = xv.y + gv.y, h2 = xv.z + gv.z, h3 = xv.w + gv.w;
  float ls = h0 + h1 + h2 + h3;
  __shared__ float red[8];
  #pragma unroll
  for (int o = 32; o; o >>= 1) ls += __shfl_xor(ls, o);
  const int lane = tid & 63, wid = tid >> 6;
  if (lane == 0) red[wid] = ls;
  __syncthreads();
  const float mu = (red[0] + red[1] + red[2] + red[3]) * (1.f / ND);
  const float d0 = h0 - mu, d1 = h1 - mu, d2 = h2 - mu, d3 = h3 - mu;
  float lv = d0 * d0 + d1 * d1 + d2 * d2 + d3 * d3;
  #pragma unroll
  for (int o = 32; o; o >>= 1) lv += __shfl_xor(lv, o);
  if (lane == 0) red[4 + wid] = lv;
  __syncthreads();
  const float rs = rsqrtf((red[4] + red[5] + red[6] + red[7]) * (1.f / ND) + 1e-5f);
  const float4 sv = ((const float4*)s)[tid];
  const float4 bv = ((const float4*)b)[tid];
  const float y0 = d0 * rs * sv.x + bv.x, y1 = d1 * rs * sv.y + bv.y;
  const float y2 = d2 * rs * sv.z + bv.z, y3 = d3 * rs * sv.w + bv.w;
  ((float4*)(x + (long)row * ND))[tid] = make_float4(y0, y1, y2, y3);
  bf16* xp = xb + (long)row * ND + tid * 4;
  xp[0] = __float2bfloat16(y0); xp[1] = __float2bfloat16(y1);
  xp[2] = __float2bfloat16(y2); xp[3] = __float2bfloat16(y3);
}

extern "C" void kernel_launch(void* const* d_in, const int* in_sizes, int n_in,
                              void* d_out, int out_size, void* d_ws, size_t ws_size,
                              hipStream_t stream) {
  const int*   tokens = (const int*)d_in[0];
  const float* emb  = (const float*)d_in[1];
  const float* Wq   = (const float*)d_in[2];
  const float* bq   = (const float*)d_in[3];
  const float* Wk   = (const float*)d_in[4];
  const float* bk   = (const float*)d_in[5];
  const float* Wv   = (const float*)d_in[6];
  const float* bv   = (const float*)d_in[7];
  const float* Wo   = (const float*)d_in[8];
  const float* bo   = (const float*)d_in[9];
  const float* rpe  = (const float*)d_in[10];
  const float* ln1s = (const float*)d_in[11];
  const float* ln1b = (const float*)d_in[12];
  const float* ln2s = (const float*)d_in[13];
  const float* ln2b = (const float*)d_in[14];
  const float* W1   = (const float*)d_in[15];
  const float* b1   = (const float*)d_in[16];
  const float* W2   = (const float*)d_in[17];
  const float* b2   = (const float*)d_in[18];
  const float* Wout = (const float*)d_in[19];
  const float* bout = (const float*)d_in[20];
  float* out = (float*)d_out;

  char* wsb = (char*)d_ws;
  size_t off = 0;
  auto take = [&](size_t bytes) -> void* {
    void* r = wsb + off;
    off = (off + bytes + 255) & ~(size_t)255;
    return r;
  };
  bf16*  wqkvT = (bf16*)take((size_t)NL * 3 * ND * ND * 2);   // [L][3][N=D][K=D]
  bf16*  woT   = (bf16*)take((size_t)NL * ND * ND * 2);
  bf16*  w1T   = (bf16*)take((size_t)NL * NF * ND * 2);       // [L][N=F][K=D]
  bf16*  w2T   = (bf16*)take((size_t)NL * ND * NF * 2);       // [L][N=D][K=F]
  bf16*  woutT = (bf16*)take((size_t)NV * ND * 2);            // [N=V][K=D]
  bf16*  rpeb  = (bf16*)take((size_t)NL * NS * NDH * 2);
  float* qkvb  = (float*)take((size_t)NL * 3 * ND * 4);
  float* x     = (float*)take((size_t)NB * NS * ND * 4);
  bf16*  xb    = (bf16*)take((size_t)NB * NS * ND * 2);
  bf16*  qkv   = (bf16*)take((size_t)3 * NB * NS * ND * 2);   // [3][B][S][D]
  bf16*  vt    = (bf16*)take((size_t)NB * NS * ND * 2);       // [B][H][Dh][S]
  bf16*  ob    = (bf16*)take((size_t)NB * NS * ND * 2);
  float* g     = (float*)take((size_t)NB * NS * NF * 4);
  bf16*  hbuf  = (bf16*)take((size_t)NB * NS * NF * 2);
  float* sc    = (float*)take((size_t)NB * NH * NS * NS * 4);
  (void)in_sizes; (void)n_in; (void)out_size; (void)ws_size;

  const dim3 tb(32, 8);
  // weight transposes (f32 -> bf16, B^T layout)
  transpose_f32_bf16<<<dim3(ND/32, ND/32, NL), tb, 0, stream>>>(Wq, wqkvT,                      ND, ND, (long)ND*ND, (long)3*ND*ND);
  transpose_f32_bf16<<<dim3(ND/32, ND/32, NL), tb, 0, stream>>>(Wk, wqkvT + (size_t)ND*ND,      ND, ND, (long)ND*ND, (long)3*ND*ND);
  transpose_f32_bf16<<<dim3(ND/32, ND/32, NL), tb, 0, stream>>>(Wv, wqkvT + (size_t)2*ND*ND,    ND, ND, (long)ND*ND, (long)3*ND*ND);
  transpose_f32_bf16<<<dim3(ND/32, ND/32, NL), tb, 0, stream>>>(Wo, woT,                        ND, ND, (long)ND*ND, (long)ND*ND);
  transpose_f32_bf16<<<dim3(NF/32, ND/32, NL), tb, 0, stream>>>(W1, w1T,                        ND, NF, (long)ND*NF, (long)NF*ND);
  transpose_f32_bf16<<<dim3(ND/32, NF/32, NL), tb, 0, stream>>>(W2, w2T,                        NF, ND, (long)NF*ND, (long)ND*NF);
  transpose_f32_bf16<<<dim3(NV/32, ND/32, 1),  tb, 0, stream>>>(Wout, woutT,                    ND, NV, 0, 0);
  cvt_bf16_k<<<(NL*NS*NDH + 255)/256, 256, 0, stream>>>(rpe, rpeb, NL*NS*NDH);
  pack3_k<<<(NL*3*ND + 255)/256, 256, 0, stream>>>(bq, bk, bv, qkvb);
  embed_k<<<NB*NS, 256, 0, stream>>>(tokens, emb, x, xb);

  for (int l = 0; l < NL; ++l) {
    // QKV projections (batched z=0,1,2), bf16 out + bias
    gemm_bt<128, 1, 0, true, 1><<<dim3(ND/128, NB*NS/128, 3), 256, 0, stream>>>(
        xb, wqkvT + (size_t)l*3*ND*ND, qkv, qkvb + (size_t)l*3*ND,
        NB*NS, ND, ND, ND, ND, ND, 1,
        0, 0, (long)ND*ND, 0, (long)NB*NS*ND, 0, ND);
    transpose_v_k<<<dim3(NS/32, 2, NB*NH), tb, 0, stream>>>(qkv + (size_t)2*NB*NS*ND, vt);
    // QK^T -> scores (f32), causal tile skip
    gemm_bt<128, 0, 1, false, 0><<<dim3(NS/128, NS/128, NB*NH), 256, 0, stream>>>(
        qkv, qkv + (size_t)NB*NS*ND, sc, nullptr,
        NS, NS, NDH, ND, ND, NS, NH,
        (long)NS*ND, 64, (long)NS*ND, 64, (long)NH*NS*NS, (long)NS*NS, 0);
    // Q @ E^T, skew-scatter-add into scores
    gemm_bt<128, 3, 3, false, 0><<<dim3(NS/128, NS/128, NB*NH), 256, 0, stream>>>(
        qkv, rpeb + (size_t)l*NS*NDH, sc, nullptr,
        NS, NS, NDH, ND, NDH, NS, NH,
        (long)NS*ND, 64, 0, 0, (long)NH*NS*NS, (long)NS*NS, 0);
    softmax_k<<<NB*NH*NS/4, 256, 0, stream>>>(sc);
    // P @ V -> attn out (bf16, scattered into (B,S,D) by head), causal kEnd
    gemm_bt<64, 1, 2, false, 0><<<dim3(1, NS/128, NB*NH), 256, 0, stream>>>(
        (const bf16*)sc, vt, ob, nullptr,
        NS, NDH, NS, 2*NS, NS, ND, NH,
        (long)NH*NS*NS*2, (long)NS*NS*2, (long)NH*NDH*NS, (long)NDH*NS, (long)NS*ND, 64, 0);
    // O projection -> g (f32) + bias
    gemm_bt<128, 0, 0, true, 1><<<dim3(ND/128, NB*NS/128, 1), 256, 0, stream>>>(
        ob, woT + (size_t)l*ND*ND, g, bo + (size_t)l*ND,
        NB*NS, ND, ND, ND, ND, ND, 1, 0,0, 0,0, 0,0, 0);
    resid_ln_k<<<NB*NS, 256, 0, stream>>>(x, g, ln1s + (size_t)l*ND, ln1b + (size_t)l*ND, xb);
    // FFN1: 256x256 pipelined kernel, bias + GELU fused, bf16 out (128 blocks)
    gemm256_bt<2, true><<<dim3(NF/256, NB*NS/256), 512, 0, stream>>>(
        xb, w1T + (size_t)l*NF*ND, hbuf, b1 + (size_t)l*NF, ND, ND, ND, NF);
    // FFN2 -> g (f32) + bias
    gemm_bt<128, 0, 0, true, 1><<<dim3(ND/128, NB*NS/128, 1), 256, 0, stream>>>(
        hbuf, w2T + (size_t)l*ND*NF, g, b2 + (size_t)l*ND,
        NB*NS, ND, NF, NF, NF, ND, 1, 0,0, 0,0, 0,0, 0);
    resid_ln_k<<<NB*NS, 256, 0, stream>>>(x, g, ln2s + (size_t)l*ND, ln2b + (size_t)l*ND, xb);
  }
  // final vocab projection: 256x256 pipelined kernel (1000 blocks), f32 out + bias
  gemm256_bt<0, true><<<dim3(NV/256, NB*NS/256), 512, 0, stream>>>(
      xb, woutT, out, bout, ND, ND, ND, NV);
}

// Round 7
// 2001.181 us; speedup vs baseline: 1.3503x; 1.3223x over previous
//
#include <hip/hip_runtime.h>
#include <hip/hip_bf16.h>
#include <cstdint>

constexpr int NB = 2, NS = 1024, ND = 1024, NH = 16, NL = 6, NV = 32000, NF = 4096, NDH = 64;

using bf16 = __hip_bfloat16;
typedef __bf16 bf16x8 __attribute__((ext_vector_type(8)));
typedef float f32x4 __attribute__((ext_vector_type(4)));

#define AS1(p) ((const __attribute__((address_space(1))) void*)(p))
#define AS3(p) ((__attribute__((address_space(3))) void*)(p))

__device__ __forceinline__ float gelu_f(float x) {
  float z = 1.5957691216057308f * (x + 0.044715f * x * x * x);
  return x / (1.f + __expf(-z));
}

// ================= 256x256 deep-pipelined GEMM (T2+T3+T4+T5) =================
template<int EP, bool HASBIAS>
__global__ __launch_bounds__(512)
void gemm256_bt(const bf16* __restrict__ A, const bf16* __restrict__ Bt,
                void* __restrict__ Cv, const float* __restrict__ bias,
                int K, int lda, int ldb, int ldc)
{
  const int nM = gridDim.y, nN = gridDim.x;
  const int nwg = nM * nN;
  const int bid = blockIdx.y * nN + blockIdx.x;
  const int qq = nwg >> 3;
  const int wg = (bid & 7) * qq + (bid >> 3);
  const int m0 = (wg % nM) * 256;
  const int n0 = (wg / nM) * 256;

  __shared__ char lds[131072];   // [buf:4][32768] ; within buf: A 16KB, B 16KB

  const int tid  = threadIdx.x;
  const int lane = tid & 63;
  const int wid  = tid >> 6;
  const int wm = (wid >> 2) * 128;   // 2 M-waves x 4 N-waves
  const int wn = (wid & 3) * 64;
  const int l15 = lane & 15;

  const int rdk = ((lane >> 4) * 16) ^ ((l15 >> 3) << 5);

  const int srow = wid * 16 + (lane >> 2);                 // 0..127
  const int scol = ((lane & 3) * 8) ^ (((lane >> 5) & 1) << 4);
  const bf16* gA = A  + (long)(m0 + srow) * lda + scol;
  const bf16* gB = Bt + (long)(n0 + srow) * ldb + scol;
  const long a128 = (long)128 * lda, b128 = (long)128 * ldb;
  char* ldsW = lds + wid * 1024;

  f32x4 acc[8][4] = {};
  const int NT = K >> 5;

#define STG(t_) do {                                                                   \
    const int b_ = ((t_) & 3) * 32768; const long ko_ = (long)(t_) * 32;               \
    __builtin_amdgcn_global_load_lds(AS1(gA + ko_),        AS3(ldsW + b_),          16, 0, 0); \
    __builtin_amdgcn_global_load_lds(AS1(gA + ko_ + a128), AS3(ldsW + b_ + 8192),   16, 0, 0); \
    __builtin_amdgcn_global_load_lds(AS1(gB + ko_),        AS3(ldsW + b_ + 16384),  16, 0, 0); \
    __builtin_amdgcn_global_load_lds(AS1(gB + ko_ + b128), AS3(ldsW + b_ + 24576),  16, 0, 0); \
  } while (0)

#define TILE(t_, vm_) do {                                                             \
    asm volatile("s_waitcnt vmcnt(" #vm_ ")" ::: "memory");                            \
    __builtin_amdgcn_s_barrier();                                                      \
    asm volatile("" ::: "memory");                                                     \
    if ((t_) + 3 < NT) STG((t_) + 3);                                                  \
    const char* la_ = lds + (((t_) & 3) * 32768);                                      \
    const char* lb_ = la_ + 16384;                                                     \
    bf16x8 bf_[4], af_[8];                                                             \
    _Pragma("unroll") for (int j_ = 0; j_ < 4; ++j_)                                   \
      bf_[j_] = *(const bf16x8*)(lb_ + (wn + j_ * 16 + l15) * 64 + rdk);               \
    _Pragma("unroll") for (int i_ = 0; i_ < 8; ++i_)                                   \
      af_[i_] = *(const bf16x8*)(la_ + (wm + i_ * 16 + l15) * 64 + rdk);               \
    __builtin_amdgcn_s_setprio(1);                                                     \
    _Pragma("unroll") for (int i_ = 0; i_ < 8; ++i_)                                   \
      _Pragma("unroll") for (int j_ = 0; j_ < 4; ++j_)                                 \
        acc[i_][j_] = __builtin_amdgcn_mfma_f32_16x16x32_bf16(af_[i_], bf_[j_], acc[i_][j_], 0, 0, 0); \
    __builtin_amdgcn_s_setprio(0);                                                     \
  } while (0)

  STG(0); STG(1); STG(2);
  int t = 0;
  for (; t < NT - 3; ++t) TILE(t, 8);
  TILE(NT - 3, 8);
  TILE(NT - 2, 4);
  TILE(NT - 1, 0);
#undef TILE
#undef STG

  const int rq = (lane >> 4) * 4;
  #pragma unroll
  for (int i = 0; i < 8; ++i) {
    const int r0 = m0 + wm + i * 16 + rq;
    #pragma unroll
    for (int j = 0; j < 4; ++j) {
      const int c = n0 + wn + j * 16 + l15;
      float bv = 0.f;
      if constexpr (HASBIAS) bv = bias[c];
      #pragma unroll
      for (int e = 0; e < 4; ++e) {
        float v = acc[i][j][e] + bv;
        if constexpr (EP == 2) v = gelu_f(v);
        if constexpr (EP == 0) ((float*)Cv)[(long)(r0 + e) * ldc + c] = v;
        else                   ((bf16*)Cv)[(long)(r0 + e) * ldc + c] = __float2bfloat16(v);
      }
    }
  }
}

// ---------------- GEMM: C[M,N] = A[M,K] @ Bt[N,K]^T (+bias) ----------------
// EP: 0=f32 out, 1=bf16 out, 2=bf16 out w/ GELU
// CZ: 0=none, 3=skip tile fully left of rel-diagonal (QE)
// SWZ: 1 = M-major tile order + bijective XCD-chunk swizzle
template<int BN, int EP, int CZ, bool HASBIAS, int SWZ>
__global__ __launch_bounds__(256)
void gemm_bt(const bf16* __restrict__ A, const bf16* __restrict__ Bt,
             void* __restrict__ Cv, const float* __restrict__ bias,
             int M, int N, int K, int lda, int ldb, int ldc, int ZH,
             long sAb, long sAh, long sBb, long sBh, long sCb, long sCh, long sBias)
{
  constexpr int BM = 128, BK = 32;
  constexpr int WGN = (BN == 128) ? 2 : 1;
  constexpr int FM  = (BM / (4 / WGN)) / 16;
  constexpr int FN  = (BN / WGN) / 16;

  const int z  = blockIdx.z;
  const int zb = z / ZH, zh = z % ZH;
  const bf16* Ab = A + (long)zb * sAb + (long)zh * sAh;
  const bf16* Bb = Bt + (long)zb * sBb + (long)zh * sBh;

  int m0, n0;
  if constexpr (SWZ == 1) {
    const int nM = gridDim.y, nN = gridDim.x;
    const int nwg = nM * nN;
    const int bid = blockIdx.y * nN + blockIdx.x;
    const int qq = nwg >> 3;
    const int wg = (bid & 7) * qq + (bid >> 3);
    m0 = (wg % nM) * BM;
    n0 = (wg / nM) * BN;
  } else {
    m0 = blockIdx.y * BM;
    n0 = blockIdx.x * BN;
  }

  if constexpr (CZ == 3) { if (m0 + n0 + BM + BN - 2 < NS - 1) return; }

  const int kEnd = K;

  __shared__ bf16 Asm[BM * BK];
  __shared__ bf16 Bsm[BN * BK];

  const int tid  = threadIdx.x;
  const int lane = tid & 63;
  const int wid  = tid >> 6;
  const int wm = (wid / WGN) * (FM * 16);
  const int wn = (wid % WGN) * (FN * 16);
  const int l15 = lane & 15;
  const int lk8 = (lane >> 4) * 8;

  f32x4 acc[FM][FN] = {};

  const int srow = tid >> 2;
  const int scol = (tid & 3) * 8;
  const bf16* gA = Ab + (long)(m0 + srow) * lda + scol;
  const bf16* gB = Bb + (long)(n0 + srow) * ldb + scol;
  bf16* ldsA = Asm + wid * 512;
  bf16* ldsB = Bsm + wid * 512;

  for (int k0 = 0; k0 < kEnd; k0 += BK) {
    __builtin_amdgcn_global_load_lds(AS1(gA + k0), AS3(ldsA), 16, 0, 0);
    __builtin_amdgcn_global_load_lds(AS1(gA + 64l * lda + k0), AS3(ldsA + 2048), 16, 0, 0);
    __builtin_amdgcn_global_load_lds(AS1(gB + k0), AS3(ldsB), 16, 0, 0);
    if constexpr (BN == 128)
      __builtin_amdgcn_global_load_lds(AS1(gB + 64l * ldb + k0), AS3(ldsB + 2048), 16, 0, 0);
    asm volatile("s_waitcnt vmcnt(0)" ::: "memory");
    __syncthreads();

    bf16x8 af[FM], bfr[FN];
    #pragma unroll
    for (int i = 0; i < FM; ++i)
      af[i] = *reinterpret_cast<const bf16x8*>(&Asm[(wm + i * 16 + l15) * BK + lk8]);
    #pragma unroll
    for (int j = 0; j < FN; ++j)
      bfr[j] = *reinterpret_cast<const bf16x8*>(&Bsm[(wn + j * 16 + l15) * BK + lk8]);
    #pragma unroll
    for (int i = 0; i < FM; ++i)
      #pragma unroll
      for (int j = 0; j < FN; ++j)
        acc[i][j] = __builtin_amdgcn_mfma_f32_16x16x32_bf16(af[i], bfr[j], acc[i][j], 0, 0, 0);
    __syncthreads();
  }

  const int rq = (lane >> 4) * 4;
  const long cb = (long)zb * sCb + (long)zh * sCh;
  #pragma unroll
  for (int i = 0; i < FM; ++i) {
    const int r0 = m0 + wm + i * 16 + rq;
    #pragma unroll
    for (int j = 0; j < FN; ++j) {
      const int c = n0 + wn + j * 16 + l15;
      float bv = 0.f;
      if constexpr (HASBIAS) bv = bias[(long)zb * sBias + c];
      #pragma unroll
      for (int e = 0; e < 4; ++e) {
        float v = acc[i][j][e] + bv;
        if constexpr (EP == 2) v = gelu_f(v);
        const long idx = cb + (long)(r0 + e) * ldc + c;
        if constexpr (EP == 0) ((float*)Cv)[idx] = v;
        else                   ((bf16*)Cv)[idx] = __float2bfloat16(v);
      }
    }
  }
}

// ================= fused flash attention (QK^T + skew-rel + softmax + PV) ===
// One block = (z, 64-row q-tile), 4 waves, each wave owns 16 q-rows.
// K/V staged per 128-k tile via global_load_lds with XOR-swizzled source
// (rule #21: linear dest + pre-swizzled src + XOR on ds_read).
// srel[q,k] = qe[q, 1023-q+k] loaded per-lane (row-contiguous over the sweep).
__global__ __launch_bounds__(256)
void flash_attn_k(const bf16* __restrict__ qkv, const bf16* __restrict__ vt,
                  const bf16* __restrict__ qe, bf16* __restrict__ ob)
{
  const int z  = blockIdx.x;           // b*16 + h
  const int qt = 15 - blockIdx.y;      // longest q-tile dispatched first
  const int b  = z >> 4, h = z & 15;
  const int q0 = qt * 64;
  const int tid  = threadIdx.x;
  const int lane = tid & 63;
  const int wid  = tid >> 6;
  const int l15  = lane & 15;
  const int g4   = lane >> 4;          // 0..3
  const int xk   = (l15 & 7) << 4;     // read-side XOR key (bytes)

  __shared__ char lds[58368];
  char* Qlds = lds;                    // [64][128B]  swizzled
  char* Klds = lds + 8192;             // [128][128B] swizzled
  char* Vlds = lds + 24576;            // [64][256B]  swizzled (d rows, k cols)
  char* Plds = lds + 40960;            // [64][272B]  padded (136 bf16/row)

  const bf16* Qg  = qkv + ((long)b * NS + q0) * ND + h * 64;
  const bf16* Kg  = qkv + (long)NB * NS * ND + (long)b * NS * ND + h * 64;
  const bf16* Vg  = vt + (long)z * 64 * NS;
  const bf16* QEg = qe + (long)z * NS * NS;

  // stage Q once: 64 rows x 8 segs(16B), XOR-preswizzled source
  #pragma unroll
  for (int i = 0; i < 2; ++i) {
    const int slot = i * 256 + tid;
    const int r = slot >> 3, seg = slot & 7;
    const int sc = (seg ^ (r & 7)) * 8;
    __builtin_amdgcn_global_load_lds(AS1(Qg + (long)r * ND + sc),
                                     AS3(Qlds + (i * 4096 + wid * 1024)), 16, 0, 0);
  }

  f32x4 aqk[8], apv[4];
  #pragma unroll
  for (int j = 0; j < 4; ++j) apv[j] = (f32x4){0.f, 0.f, 0.f, 0.f};
  float mrun[4] = {-3e38f, -3e38f, -3e38f, -3e38f};
  float lrun[4] = {0.f, 0.f, 0.f, 0.f};

  const int nk = (q0 + 191) >> 7;      // # of 128-wide k-tiles

  for (int kt = 0; kt < nk; ++kt) {
    const int k0 = kt * 128;
    __builtin_amdgcn_s_barrier();      // all waves done reading K/V of prev tile

    // stage K-tile: 128 rows x 8 segs
    #pragma unroll
    for (int i = 0; i < 4; ++i) {
      const int slot = i * 256 + tid;
      const int r = slot >> 3, seg = slot & 7;
      const int sc = (seg ^ (r & 7)) * 8;
      __builtin_amdgcn_global_load_lds(AS1(Kg + (long)(k0 + r) * ND + sc),
                                       AS3(Klds + (i * 4096 + wid * 1024)), 16, 0, 0);
    }
    // stage V-tile: 64 d-rows x 16 segs (from vt[z][d][k])
    #pragma unroll
    for (int i = 0; i < 4; ++i) {
      const int slot = i * 256 + tid;
      const int d = slot >> 4, seg = slot & 15;
      const int sc = (seg ^ (d & 7)) * 8;
      __builtin_amdgcn_global_load_lds(AS1(Vg + (long)d * NS + k0 + sc),
                                       AS3(Vlds + (i * 4096 + wid * 1024)), 16, 0, 0);
    }

    // srel loads into registers (per-lane; contiguous per q-row over k)
    unsigned short se[4][8];
    #pragma unroll
    for (int e = 0; e < 4; ++e) {
      const int qg = q0 + wid * 16 + g4 * 4 + e;
      const long rowb = (long)qg * NS;
      #pragma unroll
      for (int f = 0; f < 8; ++f) {
        int m = 1023 - qg + k0 + 16 * f + l15;
        m = m > 1023 ? 1023 : m;       // masked lanes: clamp, value discarded
        se[e][f] = *(const unsigned short*)(QEg + rowb + m);
      }
    }

    asm volatile("s_waitcnt vmcnt(0)" ::: "memory");
    __builtin_amdgcn_s_barrier();      // K/V landed for all waves

    // ---- QK^T: rows q = wid*16 + l15, k-cols 16f+l15, K-dim 64 = 2 steps
    #pragma unroll
    for (int f = 0; f < 8; ++f) aqk[f] = (f32x4){0.f, 0.f, 0.f, 0.f};
    #pragma unroll
    for (int ds = 0; ds < 2; ++ds) {
      const int ko = (ds * 32 + g4 * 8) * 2;
      bf16x8 a = *(const bf16x8*)(Qlds + (((wid * 16 + l15) * 128 + ko) ^ xk));
      #pragma unroll
      for (int f = 0; f < 8; ++f) {
        bf16x8 bb = *(const bf16x8*)(Klds + (((16 * f + l15) * 128 + ko) ^ xk));
        aqk[f] = __builtin_amdgcn_mfma_f32_16x16x32_bf16(a, bb, aqk[f], 0, 0, 0);
      }
    }

    // ---- online softmax (per lane: 4 q-rows, stats via 16-lane butterfly)
    float ps[4][8];
    float scl[4];
    #pragma unroll
    for (int e = 0; e < 4; ++e) {
      const int qg = q0 + wid * 16 + g4 * 4 + e;
      float s[8];
      float mx = mrun[e];
      #pragma unroll
      for (int f = 0; f < 8; ++f) {
        const int kg = k0 + 16 * f + l15;
        const float sv = __uint_as_float((unsigned)se[e][f] << 16);
        const float t = (aqk[f][e] + sv) * 0.125f;
        s[f] = (kg <= qg) ? t : -1e30f;
        mx = fmaxf(mx, s[f]);
      }
      #pragma unroll
      for (int o = 1; o < 16; o <<= 1) mx = fmaxf(mx, __shfl_xor(mx, o));
      const float sc_ = __expf(mrun[e] - mx);
      float ls = 0.f;
      #pragma unroll
      for (int f = 0; f < 8; ++f) { const float p = __expf(s[f] - mx); ps[e][f] = p; ls += p; }
      #pragma unroll
      for (int o = 1; o < 16; o <<= 1) ls += __shfl_xor(ls, o);
      lrun[e] = lrun[e] * sc_ + ls;
      mrun[e] = mx;
      scl[e] = sc_;
    }
    #pragma unroll
    for (int fd = 0; fd < 4; ++fd)
      #pragma unroll
      for (int e = 0; e < 4; ++e) apv[fd][e] *= scl[e];

    // P -> LDS (wave-private 16 rows), then PV
    #pragma unroll
    for (int e = 0; e < 4; ++e) {
      char* pr = Plds + (wid * 16 + g4 * 4 + e) * 272 + l15 * 2;
      #pragma unroll
      for (int f = 0; f < 8; ++f)
        *(bf16*)(pr + f * 32) = __float2bfloat16(ps[e][f]);
    }
    asm volatile("s_waitcnt lgkmcnt(0)" ::: "memory");
    __builtin_amdgcn_sched_barrier(0);  // rule #18: pin MFMA after ds_write drain

    #pragma unroll
    for (int ks = 0; ks < 4; ++ks) {
      const int ko = (ks * 32 + g4 * 8) * 2;
      bf16x8 a = *(const bf16x8*)(Plds + (wid * 16 + l15) * 272 + ko);
      #pragma unroll
      for (int fd = 0; fd < 4; ++fd) {
        bf16x8 bb = *(const bf16x8*)(Vlds + (((16 * fd + l15) * 256 + ko) ^ xk));
        apv[fd] = __builtin_amdgcn_mfma_f32_16x16x32_bf16(a, bb, apv[fd], 0, 0, 0);
      }
    }
  }

  // epilogue: O /= l, write bf16 into ob (B,S,D) at head offset
  #pragma unroll
  for (int e = 0; e < 4; ++e) {
    const float rl = 1.f / lrun[e];
    const int qg = q0 + wid * 16 + g4 * 4 + e;
    bf16* orow = ob + ((long)b * NS + qg) * ND + h * 64;
    #pragma unroll
    for (int fd = 0; fd < 4; ++fd)
      orow[16 * fd + l15] = __float2bfloat16(apv[fd][e] * rl);
  }
}

// ------------- transpose+convert: in f32 (R x C) -> out bf16 (C x R) -------------
__global__ void transpose_f32_bf16(const float* __restrict__ in, bf16* __restrict__ out,
                                   int R, int C, long inZ, long outZ) {
  __shared__ float t[32][33];
  const float* ip = in + (long)blockIdx.z * inZ;
  bf16* op = out + (long)blockIdx.z * outZ;
  const int c0 = blockIdx.x * 32, r0 = blockIdx.y * 32;
  const int tx = threadIdx.x, ty = threadIdx.y;
  #pragma unroll
  for (int i = 0; i < 4; ++i)
    t[ty * 4 + i][tx] = ip[(long)(r0 + ty * 4 + i) * C + c0 + tx];
  __syncthreads();
  #pragma unroll
  for (int i = 0; i < 4; ++i)
    op[(long)(c0 + ty * 4 + i) * R + r0 + tx] = __float2bfloat16(t[tx][ty * 4 + i]);
}

// v (B,S,D) -> vt (B,H,Dh,S)
__global__ void transpose_v_k(const bf16* __restrict__ v, bf16* __restrict__ vt) {
  __shared__ bf16 t[32][33];
  const int z = blockIdx.z, b = z >> 4, h = z & 15;
  const bf16* ip = v + (long)b * NS * ND + h * 64;
  bf16* op = vt + (long)z * 64 * NS;
  const int s0 = blockIdx.x * 32, d0 = blockIdx.y * 32;
  const int tx = threadIdx.x, ty = threadIdx.y;
  #pragma unroll
  for (int i = 0; i < 4; ++i)
    t[ty * 4 + i][tx] = ip[(long)(s0 + ty * 4 + i) * ND + d0 + tx];
  __syncthreads();
  #pragma unroll
  for (int i = 0; i < 4; ++i)
    op[(long)(d0 + ty * 4 + i) * NS + s0 + tx] = t[tx][ty * 4 + i];
}

__global__ void cvt_bf16_k(const float* __restrict__ in, bf16* __restrict__ out, int n) {
  int i = blockIdx.x * 256 + threadIdx.x;
  if (i < n) out[i] = __float2bfloat16(in[i]);
}

// pack bq,bk,bv (each L x D) -> out [L][3][D]
__global__ void pack3_k(const float* __restrict__ a, const float* __restrict__ b,
                        const float* __restrict__ c, float* __restrict__ out) {
  int i = blockIdx.x * 256 + threadIdx.x;
  if (i >= NL * 3 * ND) return;
  int d = i % ND, r = (i / ND) % 3, l = i / (3 * ND);
  const float* src = (r == 0) ? a : ((r == 1) ? b : c);
  out[i] = src[l * ND + d];
}

__global__ void embed_k(const int* __restrict__ tok, const float* __restrict__ emb,
                        float* __restrict__ x, bf16* __restrict__ xb) {
  const int row = blockIdx.x;
  const int t = tok[row];
  const float4 val = ((const float4*)(emb + (long)t * ND))[threadIdx.x];
  ((float4*)(x + (long)row * ND))[threadIdx.x] = val;
  bf16* xp = xb + (long)row * ND + threadIdx.x * 4;
  xp[0] = __float2bfloat16(val.x); xp[1] = __float2bfloat16(val.y);
  xp[2] = __float2bfloat16(val.z); xp[3] = __float2bfloat16(val.w);
}

// x = LN(x + g) * s + b (in place on x), also emit xb = bf16(x)
__global__ void resid_ln_k(float* __restrict__ x, const float* __restrict__ g,
                           const float* __restrict__ s, const float* __restrict__ b,
                           bf16* __restrict__ xb) {
  const int row = blockIdx.x, tid = threadIdx.x;
  const float4 xv = ((const float4*)(x + (long)row * ND))[tid];
  const float4 gv = ((const float4*)(g + (long)row * ND))[tid];
  float h0 = xv.x + gv.x, h1 = xv.y + gv.y, h2 = xv.z + gv.z, h3 = xv.w + gv.w;
  float ls = h0 + h1 + h2 + h3;
  __shared__ float red[8];
  #pragma unroll
  for (int o = 32; o; o >>= 1) ls += __shfl_xor(ls, o);
  const int lane = tid & 63, wid = tid >> 6;
  if (lane == 0) red[wid] = ls;
  __syncthreads();
  const float mu = (red[0] + red[1] + red[2] + red[3]) * (1.f / ND);
  const float d0 = h0 - mu, d1 = h1 - mu, d2 = h2 - mu, d3 = h3 - mu;
  float lv = d0 * d0 + d1 * d1 + d2 * d2 + d3 * d3;
  #pragma unroll
  for (int o = 32; o; o >>= 1) lv += __shfl_xor(lv, o);
  if (lane == 0) red[4 + wid] = lv;
  __syncthreads();
  const float rs = rsqrtf((red[4] + red[5] + red[6] + red[7]) * (1.f / ND) + 1e-5f);
  const float4 sv = ((const float4*)s)[tid];
  const float4 bv = ((const float4*)b)[tid];
  const float y0 = d0 * rs * sv.x + bv.x, y1 = d1 * rs * sv.y + bv.y;
  const float y2 = d2 * rs * sv.z + bv.z, y3 = d3 * rs * sv.w + bv.w;
  ((float4*)(x + (long)row * ND))[tid] = make_float4(y0, y1, y2, y3);
  bf16* xp = xb + (long)row * ND + tid * 4;
  xp[0] = __float2bfloat16(y0); xp[1] = __float2bfloat16(y1);
  xp[2] = __float2bfloat16(y2); xp[3] = __float2bfloat16(y3);
}

extern "C" void kernel_launch(void* const* d_in, const int* in_sizes, int n_in,
                              void* d_out, int out_size, void* d_ws, size_t ws_size,
                              hipStream_t stream) {
  const int*   tokens = (const int*)d_in[0];
  const float* emb  = (const float*)d_in[1];
  const float* Wq   = (const float*)d_in[2];
  const float* bq   = (const float*)d_in[3];
  const float* Wk   = (const float*)d_in[4];
  const float* bk   = (const float*)d_in[5];
  const float* Wv   = (const float*)d_in[6];
  const float* bv   = (const float*)d_in[7];
  const float* Wo   = (const float*)d_in[8];
  const float* bo   = (const float*)d_in[9];
  const float* rpe  = (const float*)d_in[10];
  const float* ln1s = (const float*)d_in[11];
  const float* ln1b = (const float*)d_in[12];
  const float* ln2s = (const float*)d_in[13];
  const float* ln2b = (const float*)d_in[14];
  const float* W1   = (const float*)d_in[15];
  const float* b1   = (const float*)d_in[16];
  const float* W2   = (const float*)d_in[17];
  const float* b2   = (const float*)d_in[18];
  const float* Wout = (const float*)d_in[19];
  const float* bout = (const float*)d_in[20];
  float* out = (float*)d_out;

  char* wsb = (char*)d_ws;
  size_t off = 0;
  auto take = [&](size_t bytes) -> void* {
    void* r = wsb + off;
    off = (off + bytes + 255) & ~(size_t)255;
    return r;
  };
  bf16*  wqkvT = (bf16*)take((size_t)NL * 3 * ND * ND * 2);   // [L][3][N=D][K=D]
  bf16*  woT   = (bf16*)take((size_t)NL * ND * ND * 2);
  bf16*  w1T   = (bf16*)take((size_t)NL * NF * ND * 2);       // [L][N=F][K=D]
  bf16*  w2T   = (bf16*)take((size_t)NL * ND * NF * 2);       // [L][N=D][K=F]
  bf16*  woutT = (bf16*)take((size_t)NV * ND * 2);            // [N=V][K=D]
  bf16*  rpeb  = (bf16*)take((size_t)NL * NS * NDH * 2);
  float* qkvb  = (float*)take((size_t)NL * 3 * ND * 4);
  float* x     = (float*)take((size_t)NB * NS * ND * 4);
  bf16*  xb    = (bf16*)take((size_t)NB * NS * ND * 2);
  bf16*  qkv   = (bf16*)take((size_t)3 * NB * NS * ND * 2);   // [3][B][S][D]
  bf16*  vt    = (bf16*)take((size_t)NB * NS * ND * 2);       // [B][H][Dh][S]
  bf16*  ob    = (bf16*)take((size_t)NB * NS * ND * 2);
  float* g     = (float*)take((size_t)NB * NS * NF * 4);
  bf16*  hbuf  = (bf16*)take((size_t)NB * NS * NF * 2);
  bf16*  qe    = (bf16*)take((size_t)NB * NH * NS * NS * 2 + 4096); // m-space QE (bf16), pad
  (void)in_sizes; (void)n_in; (void)out_size; (void)ws_size;

  const dim3 tb(32, 8);
  transpose_f32_bf16<<<dim3(ND/32, ND/32, NL), tb, 0, stream>>>(Wq, wqkvT,                      ND, ND, (long)ND*ND, (long)3*ND*ND);
  transpose_f32_bf16<<<dim3(ND/32, ND/32, NL), tb, 0, stream>>>(Wk, wqkvT + (size_t)ND*ND,      ND, ND, (long)ND*ND, (long)3*ND*ND);
  transpose_f32_bf16<<<dim3(ND/32, ND/32, NL), tb, 0, stream>>>(Wv, wqkvT + (size_t)2*ND*ND,    ND, ND, (long)ND*ND, (long)3*ND*ND);
  transpose_f32_bf16<<<dim3(ND/32, ND/32, NL), tb, 0, stream>>>(Wo, woT,                        ND, ND, (long)ND*ND, (long)ND*ND);
  transpose_f32_bf16<<<dim3(NF/32, ND/32, NL), tb, 0, stream>>>(W1, w1T,                        ND, NF, (long)ND*NF, (long)NF*ND);
  transpose_f32_bf16<<<dim3(ND/32, NF/32, NL), tb, 0, stream>>>(W2, w2T,                        NF, ND, (long)NF*ND, (long)ND*NF);
  transpose_f32_bf16<<<dim3(NV/32, ND/32, 1),  tb, 0, stream>>>(Wout, woutT,                    ND, NV, 0, 0);
  cvt_bf16_k<<<(NL*NS*NDH + 255)/256, 256, 0, stream>>>(rpe, rpeb, NL*NS*NDH);
  pack3_k<<<(NL*3*ND + 255)/256, 256, 0, stream>>>(bq, bk, bv, qkvb);
  embed_k<<<NB*NS, 256, 0, stream>>>(tokens, emb, x, xb);

  for (int l = 0; l < NL; ++l) {
    // QKV projections (batched z=0,1,2), bf16 out + bias
    gemm_bt<128, 1, 0, true, 1><<<dim3(ND/128, NB*NS/128, 3), 256, 0, stream>>>(
        xb, wqkvT + (size_t)l*3*ND*ND, qkv, qkvb + (size_t)l*3*ND,
        NB*NS, ND, ND, ND, ND, ND, 1,
        0, 0, (long)ND*ND, 0, (long)NB*NS*ND, 0, ND);
    transpose_v_k<<<dim3(NS/32, 2, NB*NH), tb, 0, stream>>>(qkv + (size_t)2*NB*NS*ND, vt);
    // Q @ E^T -> qe[z][q][m] (bf16, m-space; only live band written)
    gemm_bt<128, 1, 3, false, 0><<<dim3(NS/128, NS/128, NB*NH), 256, 0, stream>>>(
        qkv, rpeb + (size_t)l*NS*NDH, qe, nullptr,
        NS, NS, NDH, ND, NDH, NS, NH,
        (long)NS*ND, 64, 0, 0, (long)NH*NS*NS, (long)NS*NS, 0);
    // fused attention: QK^T + srel + online softmax + PV -> ob
    flash_attn_k<<<dim3(NB*NH, 16), 256, 0, stream>>>(qkv, vt, qe, ob);
    // O projection -> g (f32) + bias
    gemm_bt<128, 0, 0, true, 1><<<dim3(ND/128, NB*NS/128, 1), 256, 0, stream>>>(
        ob, woT + (size_t)l*ND*ND, g, bo + (size_t)l*ND,
        NB*NS, ND, ND, ND, ND, ND, 1, 0,0, 0,0, 0,0, 0);
    resid_ln_k<<<NB*NS, 256, 0, stream>>>(x, g, ln1s + (size_t)l*ND, ln1b + (size_t)l*ND, xb);
    // FFN1: 256x256 pipelined kernel, bias + GELU fused, bf16 out
    gemm256_bt<2, true><<<dim3(NF/256, NB*NS/256), 512, 0, stream>>>(
        xb, w1T + (size_t)l*NF*ND, hbuf, b1 + (size_t)l*NF, ND, ND, ND, NF);
    // FFN2 -> g (f32) + bias
    gemm_bt<128, 0, 0, true, 1><<<dim3(ND/128, NB*NS/128, 1), 256, 0, stream>>>(
        hbuf, w2T + (size_t)l*ND*NF, g, b2 + (size_t)l*ND,
        NB*NS, ND, NF, NF, NF, ND, 1, 0,0, 0,0, 0,0, 0);
    resid_ln_k<<<NB*NS, 256, 0, stream>>>(x, g, ln2s + (size_t)l*ND, ln2b + (size_t)l*ND, xb);
  }
  // final vocab projection: 256x256 pipelined kernel (1000 blocks), f32 out + bias
  gemm256_bt<0, true><<<dim3(NV/256, NB*NS/256), 512, 0, stream>>>(
      xb, woutT, out, bout, ND, ND, ND, NV);
}

// Round 8
// 1560.443 us; speedup vs baseline: 1.7317x; 1.2824x over previous
//
#include <hip/hip_runtime.h>
#include <hip/hip_bf16.h>
#include <cstdint>

constexpr int NB = 2, NS = 1024, ND = 1024, NH = 16, NL = 6, NV = 32000, NF = 4096, NDH = 64;

using bf16 = __hip_bfloat16;
typedef __bf16 bf16x8 __attribute__((ext_vector_type(8)));
typedef float f32x4 __attribute__((ext_vector_type(4)));

#define AS1(p) ((const __attribute__((address_space(1))) void*)(p))
#define AS3(p) ((__attribute__((address_space(3))) void*)(p))

__device__ __forceinline__ float gelu_f(float x) {
  float z = 1.5957691216057308f * (x + 0.044715f * x * x * x);
  return x / (1.f + __expf(-z));
}

// ============ 128x256 deep-pipelined GEMM, 4 waves, 2 blocks/CU =============
// C[M,N] = A[M,K] @ Bt[N,K]^T (+bias). 3-deep LDS circular buffer (72 KB),
// counted vmcnt(6) steady state (6 loads = one stage in flight), raw
// s_barrier, T2 XOR swizzle (pre-swizzled source + swizzled ds_read).
// EP: 0=f32+bias, 2=bf16 GELU+bias, 3=qkv slab-scatter bf16+bias.
// Requires M%128==0, N%256==0, K%32==0, K/32>=3, nwg%8==0.
template<int EP, bool HASBIAS>
__global__ __launch_bounds__(256)
void gemm128_bt(const bf16* __restrict__ A, const bf16* __restrict__ Bt,
                void* __restrict__ Cv, const float* __restrict__ bias,
                int K, int lda, int ldb, int ldc, long sEP)
{
  const int nM = gridDim.y, nN = gridDim.x;
  const int nwg = nM * nN;
  const int bid = blockIdx.y * nN + blockIdx.x;
  const int qq = nwg >> 3;
  const int wg = (bid & 7) * qq + (bid >> 3);
  const int m0 = (wg % nM) * 128;      // M fastest within an XCD chunk
  const int n0 = (wg / nM) * 256;

  __shared__ char lds[73728];          // 3 bufs x (A 8KB + B 16KB)

  const int tid  = threadIdx.x;
  const int lane = tid & 63;
  const int wid  = tid >> 6;           // 4 waves, each owns 128x64 of C
  const int wn   = wid * 64;
  const int l15  = lane & 15;
  const int rdk  = ((lane >> 4) * 16) ^ ((l15 >> 3) << 5);

  const int srow = wid * 16 + (lane >> 2);                    // 0..63 per call
  const int scol = ((lane & 3) * 8) ^ (((lane >> 5) & 1) << 4);
  const bf16* gA = A  + (long)(m0 + srow) * lda + scol;
  const bf16* gB = Bt + (long)(n0 + srow) * ldb + scol;
  const long a64 = 64l * lda, b64 = 64l * ldb;

  f32x4 acc[8][4] = {};
  const int NT = K >> 5;

#define STG(t_, b_) do {                                                               \
    char* dA = lds + (b_) * 24576 + wid * 1024;                                        \
    char* dB = lds + (b_) * 24576 + 8192 + wid * 1024;                                 \
    const long ko_ = (long)(t_) * 32;                                                  \
    __builtin_amdgcn_global_load_lds(AS1(gA + ko_),           AS3(dA),         16, 0, 0); \
    __builtin_amdgcn_global_load_lds(AS1(gA + ko_ + a64),     AS3(dA + 4096),  16, 0, 0); \
    __builtin_amdgcn_global_load_lds(AS1(gB + ko_),           AS3(dB),         16, 0, 0); \
    __builtin_amdgcn_global_load_lds(AS1(gB + ko_ + b64),     AS3(dB + 4096),  16, 0, 0); \
    __builtin_amdgcn_global_load_lds(AS1(gB + ko_ + 2 * b64), AS3(dB + 8192),  16, 0, 0); \
    __builtin_amdgcn_global_load_lds(AS1(gB + ko_ + 3 * b64), AS3(dB + 12288), 16, 0, 0); \
  } while (0)

#define TBODY(cur_) do {                                                               \
    const char* la_ = lds + (cur_) * 24576;                                            \
    const char* lb_ = la_ + 8192;                                                      \
    bf16x8 bf_[4], af_[8];                                                             \
    _Pragma("unroll") for (int j_ = 0; j_ < 4; ++j_)                                   \
      bf_[j_] = *(const bf16x8*)(lb_ + (wn + j_ * 16 + l15) * 64 + rdk);               \
    _Pragma("unroll") for (int i_ = 0; i_ < 8; ++i_)                                   \
      af_[i_] = *(const bf16x8*)(la_ + (i_ * 16 + l15) * 64 + rdk);                    \
    __builtin_amdgcn_s_setprio(1);                                                     \
    _Pragma("unroll") for (int i_ = 0; i_ < 8; ++i_)                                   \
      _Pragma("unroll") for (int j_ = 0; j_ < 4; ++j_)                                 \
        acc[i_][j_] = __builtin_amdgcn_mfma_f32_16x16x32_bf16(af_[i_], bf_[j_], acc[i_][j_], 0, 0, 0); \
    __builtin_amdgcn_s_setprio(0);                                                     \
  } while (0)

  STG(0, 0); STG(1, 1);
  int cur = 0, nxt = 2;
  for (int t = 0; t < NT - 1; ++t) {
    asm volatile("s_waitcnt vmcnt(6)" ::: "memory");   // stage(t) landed; stage(t+1) stays in flight
    __builtin_amdgcn_s_barrier();
    asm volatile("" ::: "memory");
    if (t + 2 < NT) STG(t + 2, nxt);                   // overwrites buf of t-1 (reads done pre-barrier)
    TBODY(cur);
    cur = (cur == 2) ? 0 : cur + 1;
    nxt = (nxt == 2) ? 0 : nxt + 1;
  }
  asm volatile("s_waitcnt vmcnt(0)" ::: "memory");
  __builtin_amdgcn_s_barrier();
  asm volatile("" ::: "memory");
  TBODY(cur);
#undef TBODY
#undef STG

  const int rq = (lane >> 4) * 4;
  #pragma unroll
  for (int i = 0; i < 8; ++i) {
    const int r0 = m0 + i * 16 + rq;
    #pragma unroll
    for (int j = 0; j < 4; ++j) {
      const int c = n0 + wn + j * 16 + l15;
      float bv = 0.f;
      if constexpr (HASBIAS) bv = bias[c];
      #pragma unroll
      for (int e = 0; e < 4; ++e) {
        float v = acc[i][j][e] + bv;
        if constexpr (EP == 0) {
          ((float*)Cv)[(long)(r0 + e) * ldc + c] = v;
        } else if constexpr (EP == 2) {
          ((bf16*)Cv)[(long)(r0 + e) * ldc + c] = __float2bfloat16(gelu_f(v));
        } else {           // EP==3: qkv slab scatter (c -> slab c>>10, col c&1023)
          ((bf16*)Cv)[(long)(c >> 10) * sEP + (long)(r0 + e) * ND + (c & 1023)] =
              __float2bfloat16(v);
        }
      }
    }
  }
}

// ---------------- GEMM: C[M,N] = A[M,K] @ Bt[N,K]^T (+bias) ----------------
// EP: 0=f32 out, 1=bf16 out.  CZ: 0=none, 3=skip tile fully left of rel-diag.
// SWZ: 1 = M-major + XCD-chunk swizzle.  KS: 1 = split-K x2 (z = k-chunk,
// partials to Cv + z*sCb; bias only on z==0).
template<int BN, int EP, int CZ, bool HASBIAS, int SWZ, int KS>
__global__ __launch_bounds__(256)
void gemm_bt(const bf16* __restrict__ A, const bf16* __restrict__ Bt,
             void* __restrict__ Cv, const float* __restrict__ bias,
             int M, int N, int K, int lda, int ldb, int ldc, int ZH,
             long sAb, long sAh, long sBb, long sBh, long sCb, long sCh, long sBias)
{
  constexpr int BM = 128, BK = 32;
  constexpr int WGN = (BN == 128) ? 2 : 1;
  constexpr int FM  = (BM / (4 / WGN)) / 16;
  constexpr int FN  = (BN / WGN) / 16;

  const int z  = blockIdx.z;
  const int zb = z / ZH, zh = z % ZH;
  const bf16* Ab = A + (long)zb * sAb + (long)zh * sAh;
  const bf16* Bb = Bt + (long)zb * sBb + (long)zh * sBh;

  int m0, n0;
  if constexpr (SWZ == 1) {
    const int nM = gridDim.y, nN = gridDim.x;
    const int nwg = nM * nN;
    const int bid = blockIdx.y * nN + blockIdx.x;
    const int qq = nwg >> 3;
    const int wg = (bid & 7) * qq + (bid >> 3);
    m0 = (wg % nM) * BM;
    n0 = (wg / nM) * BN;
  } else {
    m0 = blockIdx.y * BM;
    n0 = blockIdx.x * BN;
  }

  if constexpr (CZ == 3) { if (m0 + n0 + BM + BN - 2 < NS - 1) return; }

  int kLen = K;
  long kOff = 0;
  if constexpr (KS == 1) { kLen = K >> 1; kOff = (long)z * kLen; }

  __shared__ bf16 Asm[BM * BK];
  __shared__ bf16 Bsm[BN * BK];

  const int tid  = threadIdx.x;
  const int lane = tid & 63;
  const int wid  = tid >> 6;
  const int wm = (wid / WGN) * (FM * 16);
  const int wn = (wid % WGN) * (FN * 16);
  const int l15 = lane & 15;
  const int lk8 = (lane >> 4) * 8;

  f32x4 acc[FM][FN] = {};

  const int srow = tid >> 2;
  const int scol = (tid & 3) * 8;
  const bf16* gA = Ab + (long)(m0 + srow) * lda + scol + kOff;
  const bf16* gB = Bb + (long)(n0 + srow) * ldb + scol + kOff;
  bf16* ldsA = Asm + wid * 512;
  bf16* ldsB = Bsm + wid * 512;

  for (int k0 = 0; k0 < kLen; k0 += BK) {
    __builtin_amdgcn_global_load_lds(AS1(gA + k0), AS3(ldsA), 16, 0, 0);
    __builtin_amdgcn_global_load_lds(AS1(gA + 64l * lda + k0), AS3(ldsA + 2048), 16, 0, 0);
    __builtin_amdgcn_global_load_lds(AS1(gB + k0), AS3(ldsB), 16, 0, 0);
    if constexpr (BN == 128)
      __builtin_amdgcn_global_load_lds(AS1(gB + 64l * ldb + k0), AS3(ldsB + 2048), 16, 0, 0);
    asm volatile("s_waitcnt vmcnt(0)" ::: "memory");
    __syncthreads();

    bf16x8 af[FM], bfr[FN];
    #pragma unroll
    for (int i = 0; i < FM; ++i)
      af[i] = *reinterpret_cast<const bf16x8*>(&Asm[(wm + i * 16 + l15) * BK + lk8]);
    #pragma unroll
    for (int j = 0; j < FN; ++j)
      bfr[j] = *reinterpret_cast<const bf16x8*>(&Bsm[(wn + j * 16 + l15) * BK + lk8]);
    #pragma unroll
    for (int i = 0; i < FM; ++i)
      #pragma unroll
      for (int j = 0; j < FN; ++j)
        acc[i][j] = __builtin_amdgcn_mfma_f32_16x16x32_bf16(af[i], bfr[j], acc[i][j], 0, 0, 0);
    __syncthreads();
  }

  const int rq = (lane >> 4) * 4;
  const long cb = (long)zb * sCb + (long)zh * sCh;
  #pragma unroll
  for (int i = 0; i < FM; ++i) {
    const int r0 = m0 + wm + i * 16 + rq;
    #pragma unroll
    for (int j = 0; j < FN; ++j) {
      const int c = n0 + wn + j * 16 + l15;
      float bv = 0.f;
      if constexpr (HASBIAS) { if (KS == 0 || z == 0) bv = bias[(long)zb * sBias + c]; }
      #pragma unroll
      for (int e = 0; e < 4; ++e) {
        float v = acc[i][j][e] + bv;
        const long idx = cb + (long)(r0 + e) * ldc + c;
        if constexpr (EP == 0) ((float*)Cv)[idx] = v;
        else                   ((bf16*)Cv)[idx] = __float2bfloat16(v);
      }
    }
  }
}

// ================= fused flash attention (QK^T + skew-rel + softmax + PV) ===
__global__ __launch_bounds__(256)
void flash_attn_k(const bf16* __restrict__ qkv, const bf16* __restrict__ vt,
                  const bf16* __restrict__ qe, bf16* __restrict__ ob)
{
  const int z  = blockIdx.x;           // b*16 + h
  const int qt = 15 - blockIdx.y;      // longest q-tile dispatched first
  const int b  = z >> 4, h = z & 15;
  const int q0 = qt * 64;
  const int tid  = threadIdx.x;
  const int lane = tid & 63;
  const int wid  = tid >> 6;
  const int l15  = lane & 15;
  const int g4   = lane >> 4;          // 0..3
  const int xk   = (l15 & 7) << 4;     // read-side XOR key (bytes)

  __shared__ char lds[58368];
  char* Qlds = lds;                    // [64][128B]  swizzled
  char* Klds = lds + 8192;             // [128][128B] swizzled
  char* Vlds = lds + 24576;            // [64][256B]  swizzled (d rows, k cols)
  char* Plds = lds + 40960;            // [64][272B]  padded (136 bf16/row)

  const bf16* Qg  = qkv + ((long)b * NS + q0) * ND + h * 64;
  const bf16* Kg  = qkv + (long)NB * NS * ND + (long)b * NS * ND + h * 64;
  const bf16* Vg  = vt + (long)z * 64 * NS;
  const bf16* QEg = qe + (long)z * NS * NS;

  #pragma unroll
  for (int i = 0; i < 2; ++i) {
    const int slot = i * 256 + tid;
    const int r = slot >> 3, seg = slot & 7;
    const int sc = (seg ^ (r & 7)) * 8;
    __builtin_amdgcn_global_load_lds(AS1(Qg + (long)r * ND + sc),
                                     AS3(Qlds + (i * 4096 + wid * 1024)), 16, 0, 0);
  }

  f32x4 aqk[8], apv[4];
  #pragma unroll
  for (int j = 0; j < 4; ++j) apv[j] = (f32x4){0.f, 0.f, 0.f, 0.f};
  float mrun[4] = {-3e38f, -3e38f, -3e38f, -3e38f};
  float lrun[4] = {0.f, 0.f, 0.f, 0.f};

  const int nk = (q0 + 191) >> 7;      // # of 128-wide k-tiles

  for (int kt = 0; kt < nk; ++kt) {
    const int k0 = kt * 128;
    __builtin_amdgcn_s_barrier();

    #pragma unroll
    for (int i = 0; i < 4; ++i) {
      const int slot = i * 256 + tid;
      const int r = slot >> 3, seg = slot & 7;
      const int sc = (seg ^ (r & 7)) * 8;
      __builtin_amdgcn_global_load_lds(AS1(Kg + (long)(k0 + r) * ND + sc),
                                       AS3(Klds + (i * 4096 + wid * 1024)), 16, 0, 0);
    }
    #pragma unroll
    for (int i = 0; i < 4; ++i) {
      const int slot = i * 256 + tid;
      const int d = slot >> 4, seg = slot & 15;
      const int sc = (seg ^ (d & 7)) * 8;
      __builtin_amdgcn_global_load_lds(AS1(Vg + (long)d * NS + k0 + sc),
                                       AS3(Vlds + (i * 4096 + wid * 1024)), 16, 0, 0);
    }

    unsigned short se[4][8];
    #pragma unroll
    for (int e = 0; e < 4; ++e) {
      const int qg = q0 + wid * 16 + g4 * 4 + e;
      const long rowb = (long)qg * NS;
      #pragma unroll
      for (int f = 0; f < 8; ++f) {
        int m = 1023 - qg + k0 + 16 * f + l15;
        m = m > 1023 ? 1023 : m;
        se[e][f] = *(const unsigned short*)(QEg + rowb + m);
      }
    }

    asm volatile("s_waitcnt vmcnt(0)" ::: "memory");
    __builtin_amdgcn_s_barrier();

    #pragma unroll
    for (int f = 0; f < 8; ++f) aqk[f] = (f32x4){0.f, 0.f, 0.f, 0.f};
    #pragma unroll
    for (int ds = 0; ds < 2; ++ds) {
      const int ko = (ds * 32 + g4 * 8) * 2;
      bf16x8 a = *(const bf16x8*)(Qlds + (((wid * 16 + l15) * 128 + ko) ^ xk));
      #pragma unroll
      for (int f = 0; f < 8; ++f) {
        bf16x8 bb = *(const bf16x8*)(Klds + (((16 * f + l15) * 128 + ko) ^ xk));
        aqk[f] = __builtin_amdgcn_mfma_f32_16x16x32_bf16(a, bb, aqk[f], 0, 0, 0);
      }
    }

    float ps[4][8];
    float scl[4];
    #pragma unroll
    for (int e = 0; e < 4; ++e) {
      const int qg = q0 + wid * 16 + g4 * 4 + e;
      float s[8];
      float mx = mrun[e];
      #pragma unroll
      for (int f = 0; f < 8; ++f) {
        const int kg = k0 + 16 * f + l15;
        const float sv = __uint_as_float((unsigned)se[e][f] << 16);
        const float t = (aqk[f][e] + sv) * 0.125f;
        s[f] = (kg <= qg) ? t : -1e30f;
        mx = fmaxf(mx, s[f]);
      }
      #pragma unroll
      for (int o = 1; o < 16; o <<= 1) mx = fmaxf(mx, __shfl_xor(mx, o));
      const float sc_ = __expf(mrun[e] - mx);
      float ls = 0.f;
      #pragma unroll
      for (int f = 0; f < 8; ++f) { const float p = __expf(s[f] - mx); ps[e][f] = p; ls += p; }
      #pragma unroll
      for (int o = 1; o < 16; o <<= 1) ls += __shfl_xor(ls, o);
      lrun[e] = lrun[e] * sc_ + ls;
      mrun[e] = mx;
      scl[e] = sc_;
    }
    #pragma unroll
    for (int fd = 0; fd < 4; ++fd)
      #pragma unroll
      for (int e = 0; e < 4; ++e) apv[fd][e] *= scl[e];

    #pragma unroll
    for (int e = 0; e < 4; ++e) {
      char* pr = Plds + (wid * 16 + g4 * 4 + e) * 272 + l15 * 2;
      #pragma unroll
      for (int f = 0; f < 8; ++f)
        *(bf16*)(pr + f * 32) = __float2bfloat16(ps[e][f]);
    }
    asm volatile("s_waitcnt lgkmcnt(0)" ::: "memory");
    __builtin_amdgcn_sched_barrier(0);

    #pragma unroll
    for (int ks = 0; ks < 4; ++ks) {
      const int ko = (ks * 32 + g4 * 8) * 2;
      bf16x8 a = *(const bf16x8*)(Plds + (wid * 16 + l15) * 272 + ko);
      #pragma unroll
      for (int fd = 0; fd < 4; ++fd) {
        bf16x8 bb = *(const bf16x8*)(Vlds + (((16 * fd + l15) * 256 + ko) ^ xk));
        apv[fd] = __builtin_amdgcn_mfma_f32_16x16x32_bf16(a, bb, apv[fd], 0, 0, 0);
      }
    }
  }

  #pragma unroll
  for (int e = 0; e < 4; ++e) {
    const float rl = 1.f / lrun[e];
    const int qg = q0 + wid * 16 + g4 * 4 + e;
    bf16* orow = ob + ((long)b * NS + qg) * ND + h * 64;
    #pragma unroll
    for (int fd = 0; fd < 4; ++fd)
      orow[16 * fd + l15] = __float2bfloat16(apv[fd][e] * rl);
  }
}

// ------ vectorized transpose+convert: in f32 (R x C) -> out bf16 (C x R) ------
// 64x64 tiles, 256 threads; float4 loads, ushort4 stores.
__global__ void transpose64_k(const float* __restrict__ in, bf16* __restrict__ out,
                              int R, int C, long inZ, long outZ) {
  __shared__ float t[64][65];
  const float* ip = in + (long)blockIdx.z * inZ;
  bf16* op = out + (long)blockIdx.z * outZ;
  const int c0 = blockIdx.x * 64, r0 = blockIdx.y * 64;
  const int tid = threadIdx.x;
  const int lr = tid >> 4;          // 0..15
  const int lc = (tid & 15) * 4;    // 0,4,..,60
  #pragma unroll
  for (int i = 0; i < 4; ++i) {
    const float4 v = *(const float4*)(ip + (long)(r0 + lr + 16 * i) * C + c0 + lc);
    t[lr + 16 * i][lc]     = v.x;
    t[lr + 16 * i][lc + 1] = v.y;
    t[lr + 16 * i][lc + 2] = v.z;
    t[lr + 16 * i][lc + 3] = v.w;
  }
  __syncthreads();
  #pragma unroll
  for (int i = 0; i < 4; ++i) {
    const int oc = lr + 16 * i;     // input col = output row
    ushort4 u;
    bf16 h0 = __float2bfloat16(t[lc][oc]);
    bf16 h1 = __float2bfloat16(t[lc + 1][oc]);
    bf16 h2 = __float2bfloat16(t[lc + 2][oc]);
    bf16 h3 = __float2bfloat16(t[lc + 3][oc]);
    u.x = *(unsigned short*)&h0; u.y = *(unsigned short*)&h1;
    u.z = *(unsigned short*)&h2; u.w = *(unsigned short*)&h3;
    *(ushort4*)(op + (long)(c0 + oc) * R + r0 + lc) = u;
  }
}

// v (B,S,D) -> vt (B,H,Dh,S)
__global__ void transpose_v_k(const bf16* __restrict__ v, bf16* __restrict__ vt) {
  __shared__ bf16 t[32][33];
  const int z = blockIdx.z, b = z >> 4, h = z & 15;
  const bf16* ip = v + (long)b * NS * ND + h * 64;
  bf16* op = vt + (long)z * 64 * NS;
  const int s0 = blockIdx.x * 32, d0 = blockIdx.y * 32;
  const int tx = threadIdx.x, ty = threadIdx.y;
  #pragma unroll
  for (int i = 0; i < 4; ++i)
    t[ty * 4 + i][tx] = ip[(long)(s0 + ty * 4 + i) * ND + d0 + tx];
  __syncthreads();
  #pragma unroll
  for (int i = 0; i < 4; ++i)
    op[(long)(d0 + ty * 4 + i) * NS + s0 + tx] = t[tx][ty * 4 + i];
}

__global__ void cvt_bf16_k(const float* __restrict__ in, bf16* __restrict__ out, int n) {
  int i = blockIdx.x * 256 + threadIdx.x;
  if (i < n) out[i] = __float2bfloat16(in[i]);
}

// pack bq,bk,bv (each L x D) -> out [L][3][D]
__global__ void pack3_k(const float* __restrict__ a, const float* __restrict__ b,
                        const float* __restrict__ c, float* __restrict__ out) {
  int i = blockIdx.x * 256 + threadIdx.x;
  if (i >= NL * 3 * ND) return;
  int d = i % ND, r = (i / ND) % 3, l = i / (3 * ND);
  const float* src = (r == 0) ? a : ((r == 1) ? b : c);
  out[i] = src[l * ND + d];
}

__global__ void embed_k(const int* __restrict__ tok, const float* __restrict__ emb,
                        float* __restrict__ x, bf16* __restrict__ xb) {
  const int row = blockIdx.x;
  const int t = tok[row];
  const float4 val = ((const float4*)(emb + (long)t * ND))[threadIdx.x];
  ((float4*)(x + (long)row * ND))[threadIdx.x] = val;
  bf16* xp = xb + (long)row * ND + threadIdx.x * 4;
  xp[0] = __float2bfloat16(val.x); xp[1] = __float2bfloat16(val.y);
  xp[2] = __float2bfloat16(val.z); xp[3] = __float2bfloat16(val.w);
}

// x = LN(x + g0 + g1) * s + b (in place on x), also emit xb = bf16(x)
__global__ void resid_ln_k(float* __restrict__ x, const float* __restrict__ g0,
                           const float* __restrict__ g1,
                           const float* __restrict__ s, const float* __restrict__ b,
                           bf16* __restrict__ xb) {
  const int row = blockIdx.x, tid = threadIdx.x;
  const float4 xv = ((const float4*)(x + (long)row * ND))[tid];
  const float4 ga = ((const float4*)(g0 + (long)row * ND))[tid];
  const float4 gb = ((const float4*)(g1 + (long)row * ND))[tid];
  float h0 = xv.x + ga.x + gb.x, h1 = xv.y + ga.y + gb.y;
  float h2 = xv.z + ga.z + gb.z, h3 = xv.w + ga.w + gb.w;
  float ls = h0 + h1 + h2 + h3;
  __shared__ float red[8];
  #pragma unroll
  for (int o = 32; o; o >>= 1) ls += __shfl_xor(ls, o);
  const int lane = tid & 63, wid = tid >> 6;
  if (lane == 0) red[wid] = ls;
  __syncthreads();
  const float mu = (red[0] + red[1] + red[2] + red[3]) * (1.f / ND);
  const float d0 = h0 - mu, d1 = h1 - mu, d2 = h2 - mu, d3 = h3 - mu;
  float lv = d0 * d0 + d1 * d1 + d2 * d2 + d3 * d3;
  #pragma unroll
  for (int o = 32; o; o >>= 1) lv += __shfl_xor(lv, o);
  if (lane == 0) red[4 + wid] = lv;
  __syncthreads();
  const float rs = rsqrtf((red[4] + red[5] + red[6] + red[7]) * (1.f / ND) + 1e-5f);
  const float4 sv = ((const float4*)s)[tid];
  const float4 bv = ((const float4*)b)[tid];
  const float y0 = d0 * rs * sv.x + bv.x, y1 = d1 * rs * sv.y + bv.y;
  const float y2 = d2 * rs * sv.z + bv.z, y3 = d3 * rs * sv.w + bv.w;
  ((float4*)(x + (long)row * ND))[tid] = make_float4(y0, y1, y2, y3);
  bf16* xp = xb + (long)row * ND + tid * 4;
  xp[0] = __float2bfloat16(y0); xp[1] = __float2bfloat16(y1);
  xp[2] = __float2bfloat16(y2); xp[3] = __float2bfloat16(y3);
}

extern "C" void kernel_launch(void* const* d_in, const int* in_sizes, int n_in,
                              void* d_out, int out_size, void* d_ws, size_t ws_size,
                              hipStream_t stream) {
  const int*   tokens = (const int*)d_in[0];
  const float* emb  = (const float*)d_in[1];
  const float* Wq   = (const float*)d_in[2];
  const float* bq   = (const float*)d_in[3];
  const float* Wk   = (const float*)d_in[4];
  const float* bk   = (const float*)d_in[5];
  const float* Wv   = (const float*)d_in[6];
  const float* bv   = (const float*)d_in[7];
  const float* Wo   = (const float*)d_in[8];
  const float* bo   = (const float*)d_in[9];
  const float* rpe  = (const float*)d_in[10];
  const float* ln1s = (const float*)d_in[11];
  const float* ln1b = (const float*)d_in[12];
  const float* ln2s = (const float*)d_in[13];
  const float* ln2b = (const float*)d_in[14];
  const float* W1   = (const float*)d_in[15];
  const float* b1   = (const float*)d_in[16];
  const float* W2   = (const float*)d_in[17];
  const float* b2   = (const float*)d_in[18];
  const float* Wout = (const float*)d_in[19];
  const float* bout = (const float*)d_in[20];
  float* out = (float*)d_out;

  char* wsb = (char*)d_ws;
  size_t off = 0;
  auto take = [&](size_t bytes) -> void* {
    void* r = wsb + off;
    off = (off + bytes + 255) & ~(size_t)255;
    return r;
  };
  bf16*  wqkvT = (bf16*)take((size_t)NL * 3 * ND * ND * 2);   // [L][3][N=D][K=D]
  bf16*  woT   = (bf16*)take((size_t)NL * ND * ND * 2);
  bf16*  w1T   = (bf16*)take((size_t)NL * NF * ND * 2);       // [L][N=F][K=D]
  bf16*  w2T   = (bf16*)take((size_t)NL * ND * NF * 2);       // [L][N=D][K=F]
  bf16*  woutT = (bf16*)take((size_t)NV * ND * 2);            // [N=V][K=D]
  bf16*  rpeb  = (bf16*)take((size_t)NL * NS * NDH * 2);
  float* qkvb  = (float*)take((size_t)NL * 3 * ND * 4);
  float* x     = (float*)take((size_t)NB * NS * ND * 4);
  bf16*  xb    = (bf16*)take((size_t)NB * NS * ND * 2);
  bf16*  qkv   = (bf16*)take((size_t)3 * NB * NS * ND * 2);   // [3][B][S][D]
  bf16*  vt    = (bf16*)take((size_t)NB * NS * ND * 2);       // [B][H][Dh][S]
  bf16*  ob    = (bf16*)take((size_t)NB * NS * ND * 2);
  float* g     = (float*)take((size_t)2 * NB * NS * ND * 4);  // split-K partials g0,g1
  bf16*  hbuf  = (bf16*)take((size_t)NB * NS * NF * 2);
  bf16*  qe    = (bf16*)take((size_t)NB * NH * NS * NS * 2 + 4096);
  (void)in_sizes; (void)n_in; (void)out_size; (void)ws_size;

  const long gStride = (long)NB * NS * ND;   // f32 elems between g0 and g1

  // weight transposes (f32 -> bf16, B^T layout), vectorized 64x64
  transpose64_k<<<dim3(ND/64, ND/64, NL), 256, 0, stream>>>(Wq, wqkvT,                   ND, ND, (long)ND*ND, (long)3*ND*ND);
  transpose64_k<<<dim3(ND/64, ND/64, NL), 256, 0, stream>>>(Wk, wqkvT + (size_t)ND*ND,   ND, ND, (long)ND*ND, (long)3*ND*ND);
  transpose64_k<<<dim3(ND/64, ND/64, NL), 256, 0, stream>>>(Wv, wqkvT + (size_t)2*ND*ND, ND, ND, (long)ND*ND, (long)3*ND*ND);
  transpose64_k<<<dim3(ND/64, ND/64, NL), 256, 0, stream>>>(Wo, woT,                     ND, ND, (long)ND*ND, (long)ND*ND);
  transpose64_k<<<dim3(NF/64, ND/64, NL), 256, 0, stream>>>(W1, w1T,                     ND, NF, (long)ND*NF, (long)NF*ND);
  transpose64_k<<<dim3(ND/64, NF/64, NL), 256, 0, stream>>>(W2, w2T,                     NF, ND, (long)NF*ND, (long)ND*NF);
  transpose64_k<<<dim3(NV/64, ND/64, 1),  256, 0, stream>>>(Wout, woutT,                 ND, NV, 0, 0);
  cvt_bf16_k<<<(NL*NS*NDH + 255)/256, 256, 0, stream>>>(rpe, rpeb, NL*NS*NDH);
  pack3_k<<<(NL*3*ND + 255)/256, 256, 0, stream>>>(bq, bk, bv, qkvb);
  embed_k<<<NB*NS, 256, 0, stream>>>(tokens, emb, x, xb);

  const dim3 tb(32, 8);
  for (int l = 0; l < NL; ++l) {
    // QKV fused (N=3072) on pipelined 128x256 kernel, slab-scatter epilogue
    gemm128_bt<3, true><<<dim3(3*ND/256, NB*NS/128), 256, 0, stream>>>(
        xb, wqkvT + (size_t)l*3*ND*ND, qkv, qkvb + (size_t)l*3*ND,
        ND, ND, ND, ND, gStride);
    transpose_v_k<<<dim3(NS/32, 2, NB*NH), tb, 0, stream>>>(qkv + (size_t)2*NB*NS*ND, vt);
    // Q @ E^T -> qe[z][q][m] (bf16, m-space; only live band written)
    gemm_bt<128, 1, 3, false, 0, 0><<<dim3(NS/128, NS/128, NB*NH), 256, 0, stream>>>(
        qkv, rpeb + (size_t)l*NS*NDH, qe, nullptr,
        NS, NS, NDH, ND, NDH, NS, NH,
        (long)NS*ND, 64, 0, 0, (long)NH*NS*NS, (long)NS*NS, 0);
    // fused attention
    flash_attn_k<<<dim3(NB*NH, 16), 256, 0, stream>>>(qkv, vt, qe, ob);
    // O projection, split-K x2 -> g0,g1 (f32; bias on z==0)
    gemm_bt<128, 0, 0, true, 1, 1><<<dim3(ND/128, NB*NS/128, 2), 256, 0, stream>>>(
        ob, woT + (size_t)l*ND*ND, g, bo + (size_t)l*ND,
        NB*NS, ND, ND, ND, ND, ND, 1, 0,0, 0,0, gStride, 0, 0);
    resid_ln_k<<<NB*NS, 256, 0, stream>>>(x, g, g + gStride,
        ln1s + (size_t)l*ND, ln1b + (size_t)l*ND, xb);
    // FFN1 on pipelined 128x256 kernel, bias + GELU, bf16 out (256 blocks)
    gemm128_bt<2, true><<<dim3(NF/256, NB*NS/128), 256, 0, stream>>>(
        xb, w1T + (size_t)l*NF*ND, hbuf, b1 + (size_t)l*NF, ND, ND, ND, NF, 0);
    // FFN2, split-K x2 (K=4096 -> 2x2048) -> g0,g1
    gemm_bt<128, 0, 0, true, 1, 1><<<dim3(ND/128, NB*NS/128, 2), 256, 0, stream>>>(
        hbuf, w2T + (size_t)l*ND*NF, g, b2 + (size_t)l*ND,
        NB*NS, ND, NF, NF, NF, ND, 1, 0,0, 0,0, gStride, 0, 0);
    resid_ln_k<<<NB*NS, 256, 0, stream>>>(x, g, g + gStride,
        ln2s + (size_t)l*ND, ln2b + (size_t)l*ND, xb);
  }
  // final vocab projection on pipelined 128x256 kernel (2000 blocks)
  gemm128_bt<0, true><<<dim3(NV/256, NB*NS/128), 256, 0, stream>>>(
      xb, woutT, out, bout, ND, ND, ND, NV, 0);
}

// Round 9
// 1357.937 us; speedup vs baseline: 1.9899x; 1.1491x over previous
//
#include <hip/hip_runtime.h>
#include <hip/hip_bf16.h>
#include <cstdint>

constexpr int NB = 2, NS = 1024, ND = 1024, NH = 16, NL = 6, NV = 32000, NF = 4096, NDH = 64;

using bf16 = __hip_bfloat16;
typedef __bf16 bf16x8 __attribute__((ext_vector_type(8)));
typedef float f32x4 __attribute__((ext_vector_type(4)));

#define AS1(p) ((const __attribute__((address_space(1))) void*)(p))
#define AS3(p) ((__attribute__((address_space(3))) void*)(p))

__device__ __forceinline__ float gelu_f(float x) {
  float z = 1.5957691216057308f * (x + 0.044715f * x * x * x);
  return x / (1.f + __expf(-z));
}

// ================= 256x256 8-PHASE pipelined GEMM (T2+T3+T4+T5) =============
// 8 waves, BK=64 K-tiles, 2 LDS bufs x 4 planes {Aklo,Akhi,Bklo,Bkhi} x 16KB.
// Per phase: vmcnt(N) -> barrier -> ds_read subtile -> stage 1 plane ->
// setprio(1) 16 MFMA setprio(0) -> barrier.  Steady vmcnt 10/12; planes are
// staged 5-8 phases before first read; every stage targets a plane whose last
// reader passed >=1 barrier earlier (schedule derived in journal).
// Requires M%256==0, N%256==0, K%128==0 (NT=K/64 even >=2), nwg%8==0.
template<int EP, bool HASBIAS>
__global__ __launch_bounds__(512)
void gemm256p(const bf16* __restrict__ A, const bf16* __restrict__ Bt,
              void* __restrict__ Cv, const float* __restrict__ bias,
              int K, int lda, int ldb, int ldc)
{
  const int nM = gridDim.y, nN = gridDim.x;
  const int nwg = nM * nN;
  const int bid = blockIdx.y * nN + blockIdx.x;
  const int wg = (bid & 7) * (nwg >> 3) + (bid >> 3);
  const int m0 = (wg % nM) * 256;
  const int n0 = (wg / nM) * 256;

  __shared__ char lds[131072];   // buf b at b*65536: Aklo 0, Akhi 16K, Bklo 32K, Bkhi 48K

  const int tid = threadIdx.x, lane = tid & 63, wid = tid >> 6;
  const int wm = (wid >> 2) * 128;   // 2 M-waves x 4 N-waves
  const int wn = (wid & 3) * 64;
  const int l15 = lane & 15, g4 = lane >> 4;
  const int rdk = (g4 * 16) ^ ((l15 >> 3) << 5);

  const int srow = wid * 16 + (lane >> 2);
  const int scol = ((lane & 3) * 8) ^ (((lane >> 5) & 1) << 4);
  const bf16* gA = A  + (long)(m0 + srow) * lda + scol;
  const bf16* gB = Bt + (long)(n0 + srow) * ldb + scol;
  const long a128 = 128l * lda, b128 = 128l * ldb;

  f32x4 acc[8][4] = {};
  const int NT = K >> 6;

#define SGA(bufsel_, t_, kc_) do {                                                     \
    char* d_ = lds + (bufsel_) * 65536 + (kc_) * 16384 + wid * 1024;                   \
    const long ko_ = (long)(t_) * 64 + (kc_) * 32;                                     \
    __builtin_amdgcn_global_load_lds(AS1(gA + ko_),        AS3(d_),        16, 0, 0);  \
    __builtin_amdgcn_global_load_lds(AS1(gA + ko_ + a128), AS3(d_ + 8192), 16, 0, 0);  \
  } while (0)
#define SGB(bufsel_, t_, kc_) do {                                                     \
    char* d_ = lds + (bufsel_) * 65536 + 32768 + (kc_) * 16384 + wid * 1024;           \
    const long ko_ = (long)(t_) * 64 + (kc_) * 32;                                     \
    __builtin_amdgcn_global_load_lds(AS1(gB + ko_),        AS3(d_),        16, 0, 0);  \
    __builtin_amdgcn_global_load_lds(AS1(gB + ko_ + b128), AS3(d_ + 8192), 16, 0, 0);  \
  } while (0)

  // phase: vmcnt -> barrier -> reads -> stage -> MFMA(16) -> barrier
#define PH(vm_, bufsel_, kc_, ih_, RDB_, STGX_) do {                                   \
    asm volatile("s_waitcnt vmcnt(" #vm_ ")" ::: "memory");                            \
    __builtin_amdgcn_s_barrier();                                                      \
    asm volatile("" ::: "memory");                                                     \
    const char* la_ = lds + (bufsel_) * 65536 + (kc_) * 16384;                         \
    const char* lb_ = lds + (bufsel_) * 65536 + 32768 + (kc_) * 16384;                 \
    if (RDB_) {                                                                        \
      _Pragma("unroll") for (int j_ = 0; j_ < 4; ++j_)                                 \
        bfr[j_] = *(const bf16x8*)(lb_ + (wn + j_ * 16 + l15) * 64 + rdk);             \
    }                                                                                  \
    bf16x8 af_[4];                                                                     \
    _Pragma("unroll") for (int i2_ = 0; i2_ < 4; ++i2_)                                \
      af_[i2_] = *(const bf16x8*)(la_ + (wm + (ih_) * 64 + i2_ * 16 + l15) * 64 + rdk);\
    STGX_;                                                                             \
    __builtin_amdgcn_s_setprio(1);                                                     \
    _Pragma("unroll") for (int i2_ = 0; i2_ < 4; ++i2_)                                \
      _Pragma("unroll") for (int j_ = 0; j_ < 4; ++j_)                                 \
        acc[(ih_) * 4 + i2_][j_] = __builtin_amdgcn_mfma_f32_16x16x32_bf16(            \
            af_[i2_], bfr[j_], acc[(ih_) * 4 + i2_][j_], 0, 0, 0);                     \
    __builtin_amdgcn_s_setprio(0);                                                     \
    asm volatile("" ::: "memory");                                                     \
    __builtin_amdgcn_s_barrier();                                                      \
  } while (0)

  // prologue: 7 stages in steady order (ph2..ph8 equivalents)
  SGB(0, 0, 0);  // Bklo(t0)
  SGA(0, 0, 0);  // Aklo(t0)
  SGB(0, 0, 1);  // Bkhi(t0)
  SGA(0, 0, 1);  // Akhi(t0)
  SGB(1, 1, 0);  // Bklo(t1)
  SGA(1, 1, 0);  // Aklo(t1)
  SGB(1, 1, 1);  // Bkhi(t1)

  for (int i = 0; i < (NT >> 1) - 1; ++i) {
    const int t1 = 2 * i + 1, t2 = 2 * i + 2, t3 = 2 * i + 3;
    bf16x8 bfr[4];
    PH(10, 0, 0, 0, 1, SGA(1, t1, 1));   // ph1: complete t1 (Akhi')
    PH(12, 0, 0, 1, 0, SGB(0, t2, 0));   // ph2
    PH(10, 0, 1, 0, 1, SGA(0, t2, 0));   // ph3
    PH(12, 0, 1, 1, 0, SGB(0, t2, 1));   // ph4
    PH(10, 1, 0, 0, 1, SGA(0, t2, 1));   // ph5
    PH(12, 1, 0, 1, 0, SGB(1, t3, 0));   // ph6
    PH(10, 1, 1, 0, 1, SGA(1, t3, 0));   // ph7
    PH(12, 1, 1, 1, 0, SGB(1, t3, 1));   // ph8
  }
  { // peeled last iteration (no prefetch; exact drain counts)
    const int t1 = NT - 1;
    bf16x8 bfr[4];
    PH(10, 0, 0, 0, 1, SGA(1, t1, 1));
    PH(12, 0, 0, 1, 0, (void)0);
    PH( 8, 0, 1, 0, 1, (void)0);
    PH( 8, 0, 1, 1, 0, (void)0);
    PH( 4, 1, 0, 0, 1, (void)0);
    PH( 4, 1, 0, 1, 0, (void)0);
    PH( 0, 1, 1, 0, 1, (void)0);
    PH( 0, 1, 1, 1, 0, (void)0);
  }
#undef PH
#undef SGA
#undef SGB

  const int rq = (lane >> 4) * 4;
  #pragma unroll
  for (int i = 0; i < 8; ++i) {
    const int r0 = m0 + wm + i * 16 + rq;
    #pragma unroll
    for (int j = 0; j < 4; ++j) {
      const int c = n0 + wn + j * 16 + l15;
      float bv = 0.f;
      if constexpr (HASBIAS) bv = bias[c];
      #pragma unroll
      for (int e = 0; e < 4; ++e) {
        float v = acc[i][j][e] + bv;
        if constexpr (EP == 2) v = gelu_f(v);
        if constexpr (EP == 0) ((float*)Cv)[(long)(r0 + e) * ldc + c] = v;
        else                   ((bf16*)Cv)[(long)(r0 + e) * ldc + c] = __float2bfloat16(v);
      }
    }
  }
}

// ============ 128x256 deep-pipelined GEMM, 4 waves, 2 blocks/CU =============
// 3-deep circular buffer, counted vmcnt(6). EP: 0=f32+bias (KSZ>1: z-slab at
// Cv + z*sEP), 2=bf16 GELU+bias, 3=qkv slab-scatter bf16+bias.
// KSZ: split-K factor (z = blockIdx.z), bias applied on z==0 only.
template<int EP, bool HASBIAS, int KSZ>
__global__ __launch_bounds__(256)
void gemm128_bt(const bf16* __restrict__ A, const bf16* __restrict__ Bt,
                void* __restrict__ Cv, const float* __restrict__ bias,
                int K, int lda, int ldb, int ldc, long sEP)
{
  const int nM = gridDim.y, nN = gridDim.x;
  const int nwg = nM * nN;
  const int bid = blockIdx.y * nN + blockIdx.x;
  const int qq = nwg >> 3;
  const int wg = (bid & 7) * qq + (bid >> 3);
  const int m0 = (wg % nM) * 128;
  const int n0 = (wg / nM) * 256;

  const int kLen = K / KSZ;
  const long kOff = (long)blockIdx.z * kLen;

  __shared__ char lds[73728];          // 3 bufs x (A 8KB + B 16KB)

  const int tid  = threadIdx.x;
  const int lane = tid & 63;
  const int wid  = tid >> 6;
  const int wn   = wid * 64;
  const int l15  = lane & 15;
  const int rdk  = ((lane >> 4) * 16) ^ ((l15 >> 3) << 5);

  const int srow = wid * 16 + (lane >> 2);
  const int scol = ((lane & 3) * 8) ^ (((lane >> 5) & 1) << 4);
  const bf16* gA = A  + (long)(m0 + srow) * lda + scol + kOff;
  const bf16* gB = Bt + (long)(n0 + srow) * ldb + scol + kOff;
  const long a64 = 64l * lda, b64 = 64l * ldb;

  f32x4 acc[8][4] = {};
  const int NT = kLen >> 5;

#define STG(t_, b_) do {                                                               \
    char* dA = lds + (b_) * 24576 + wid * 1024;                                        \
    char* dB = lds + (b_) * 24576 + 8192 + wid * 1024;                                 \
    const long ko_ = (long)(t_) * 32;                                                  \
    __builtin_amdgcn_global_load_lds(AS1(gA + ko_),           AS3(dA),         16, 0, 0); \
    __builtin_amdgcn_global_load_lds(AS1(gA + ko_ + a64),     AS3(dA + 4096),  16, 0, 0); \
    __builtin_amdgcn_global_load_lds(AS1(gB + ko_),           AS3(dB),         16, 0, 0); \
    __builtin_amdgcn_global_load_lds(AS1(gB + ko_ + b64),     AS3(dB + 4096),  16, 0, 0); \
    __builtin_amdgcn_global_load_lds(AS1(gB + ko_ + 2 * b64), AS3(dB + 8192),  16, 0, 0); \
    __builtin_amdgcn_global_load_lds(AS1(gB + ko_ + 3 * b64), AS3(dB + 12288), 16, 0, 0); \
  } while (0)

#define TBODY(cur_) do {                                                               \
    const char* la_ = lds + (cur_) * 24576;                                            \
    const char* lb_ = la_ + 8192;                                                      \
    bf16x8 bf_[4], af_[8];                                                             \
    _Pragma("unroll") for (int j_ = 0; j_ < 4; ++j_)                                   \
      bf_[j_] = *(const bf16x8*)(lb_ + (wn + j_ * 16 + l15) * 64 + rdk);               \
    _Pragma("unroll") for (int i_ = 0; i_ < 8; ++i_)                                   \
      af_[i_] = *(const bf16x8*)(la_ + (i_ * 16 + l15) * 64 + rdk);                    \
    __builtin_amdgcn_s_setprio(1);                                                     \
    _Pragma("unroll") for (int i_ = 0; i_ < 8; ++i_)                                   \
      _Pragma("unroll") for (int j_ = 0; j_ < 4; ++j_)                                 \
        acc[i_][j_] = __builtin_amdgcn_mfma_f32_16x16x32_bf16(af_[i_], bf_[j_], acc[i_][j_], 0, 0, 0); \
    __builtin_amdgcn_s_setprio(0);                                                     \
  } while (0)

  STG(0, 0); STG(1, 1);
  int cur = 0, nxt = 2;
  for (int t = 0; t < NT - 1; ++t) {
    asm volatile("s_waitcnt vmcnt(6)" ::: "memory");
    __builtin_amdgcn_s_barrier();
    asm volatile("" ::: "memory");
    if (t + 2 < NT) STG(t + 2, nxt);
    TBODY(cur);
    cur = (cur == 2) ? 0 : cur + 1;
    nxt = (nxt == 2) ? 0 : nxt + 1;
  }
  asm volatile("s_waitcnt vmcnt(0)" ::: "memory");
  __builtin_amdgcn_s_barrier();
  asm volatile("" ::: "memory");
  TBODY(cur);
#undef TBODY
#undef STG

  const int rq = (lane >> 4) * 4;
  #pragma unroll
  for (int i = 0; i < 8; ++i) {
    const int r0 = m0 + i * 16 + rq;
    #pragma unroll
    for (int j = 0; j < 4; ++j) {
      const int c = n0 + wn + j * 16 + l15;
      float bv = 0.f;
      if constexpr (HASBIAS) { if (KSZ == 1 || blockIdx.z == 0) bv = bias[c]; }
      #pragma unroll
      for (int e = 0; e < 4; ++e) {
        float v = acc[i][j][e] + bv;
        if constexpr (EP == 0) {
          float* Cz = (float*)Cv + (KSZ > 1 ? (long)blockIdx.z * sEP : 0);
          Cz[(long)(r0 + e) * ldc + c] = v;
        } else if constexpr (EP == 2) {
          ((bf16*)Cv)[(long)(r0 + e) * ldc + c] = __float2bfloat16(gelu_f(v));
        } else {           // EP==3: qkv slab scatter
          ((bf16*)Cv)[(long)(c >> 10) * sEP + (long)(r0 + e) * ND + (c & 1023)] =
              __float2bfloat16(v);
        }
      }
    }
  }
}

// ---------------- gemm_bt (QE only): C=A@Bt^T, CZ=3 band skip, bf16 out -----
template<int BN, int EP, int CZ, bool HASBIAS, int SWZ, int KS>
__global__ __launch_bounds__(256)
void gemm_bt(const bf16* __restrict__ A, const bf16* __restrict__ Bt,
             void* __restrict__ Cv, const float* __restrict__ bias,
             int M, int N, int K, int lda, int ldb, int ldc, int ZH,
             long sAb, long sAh, long sBb, long sBh, long sCb, long sCh, long sBias)
{
  constexpr int BM = 128, BK = 32;
  constexpr int WGN = (BN == 128) ? 2 : 1;
  constexpr int FM  = (BM / (4 / WGN)) / 16;
  constexpr int FN  = (BN / WGN) / 16;

  const int z  = blockIdx.z;
  const int zb = z / ZH, zh = z % ZH;
  const bf16* Ab = A + (long)zb * sAb + (long)zh * sAh;
  const bf16* Bb = Bt + (long)zb * sBb + (long)zh * sBh;

  const int m0 = blockIdx.y * BM;
  const int n0 = blockIdx.x * BN;

  if constexpr (CZ == 3) { if (m0 + n0 + BM + BN - 2 < NS - 1) return; }

  __shared__ bf16 Asm[BM * BK];
  __shared__ bf16 Bsm[BN * BK];

  const int tid  = threadIdx.x;
  const int lane = tid & 63;
  const int wid  = tid >> 6;
  const int wm = (wid / WGN) * (FM * 16);
  const int wn = (wid % WGN) * (FN * 16);
  const int l15 = lane & 15;
  const int lk8 = (lane >> 4) * 8;

  f32x4 acc[FM][FN] = {};

  const int srow = tid >> 2;
  const int scol = (tid & 3) * 8;
  const bf16* gA = Ab + (long)(m0 + srow) * lda + scol;
  const bf16* gB = Bb + (long)(n0 + srow) * ldb + scol;
  bf16* ldsA = Asm + wid * 512;
  bf16* ldsB = Bsm + wid * 512;

  for (int k0 = 0; k0 < K; k0 += BK) {
    __builtin_amdgcn_global_load_lds(AS1(gA + k0), AS3(ldsA), 16, 0, 0);
    __builtin_amdgcn_global_load_lds(AS1(gA + 64l * lda + k0), AS3(ldsA + 2048), 16, 0, 0);
    __builtin_amdgcn_global_load_lds(AS1(gB + k0), AS3(ldsB), 16, 0, 0);
    if constexpr (BN == 128)
      __builtin_amdgcn_global_load_lds(AS1(gB + 64l * ldb + k0), AS3(ldsB + 2048), 16, 0, 0);
    asm volatile("s_waitcnt vmcnt(0)" ::: "memory");
    __syncthreads();

    bf16x8 af[FM], bfr[FN];
    #pragma unroll
    for (int i = 0; i < FM; ++i)
      af[i] = *reinterpret_cast<const bf16x8*>(&Asm[(wm + i * 16 + l15) * BK + lk8]);
    #pragma unroll
    for (int j = 0; j < FN; ++j)
      bfr[j] = *reinterpret_cast<const bf16x8*>(&Bsm[(wn + j * 16 + l15) * BK + lk8]);
    #pragma unroll
    for (int i = 0; i < FM; ++i)
      #pragma unroll
      for (int j = 0; j < FN; ++j)
        acc[i][j] = __builtin_amdgcn_mfma_f32_16x16x32_bf16(af[i], bfr[j], acc[i][j], 0, 0, 0);
    __syncthreads();
  }

  const int rq = (lane >> 4) * 4;
  const long cb = (long)zb * sCb + (long)zh * sCh;
  #pragma unroll
  for (int i = 0; i < FM; ++i) {
    const int r0 = m0 + wm + i * 16 + rq;
    #pragma unroll
    for (int j = 0; j < FN; ++j) {
      const int c = n0 + wn + j * 16 + l15;
      float bv = 0.f;
      if constexpr (HASBIAS) bv = bias[(long)zb * sBias + c];
      #pragma unroll
      for (int e = 0; e < 4; ++e) {
        float v = acc[i][j][e] + bv;
        const long idx = cb + (long)(r0 + e) * ldc + c;
        if constexpr (EP == 0) ((float*)Cv)[idx] = v;
        else                   ((bf16*)Cv)[idx] = __float2bfloat16(v);
      }
    }
  }
}

// ================= fused flash attention (QK^T + skew-rel + softmax + PV) ===
__global__ __launch_bounds__(256)
void flash_attn_k(const bf16* __restrict__ qkv, const bf16* __restrict__ vt,
                  const bf16* __restrict__ qe, bf16* __restrict__ ob)
{
  const int z  = blockIdx.x;
  const int qt = 15 - blockIdx.y;
  const int b  = z >> 4, h = z & 15;
  const int q0 = qt * 64;
  const int tid  = threadIdx.x;
  const int lane = tid & 63;
  const int wid  = tid >> 6;
  const int l15  = lane & 15;
  const int g4   = lane >> 4;
  const int xk   = (l15 & 7) << 4;

  __shared__ char lds[58368];
  char* Qlds = lds;
  char* Klds = lds + 8192;
  char* Vlds = lds + 24576;
  char* Plds = lds + 40960;

  const bf16* Qg  = qkv + ((long)b * NS + q0) * ND + h * 64;
  const bf16* Kg  = qkv + (long)NB * NS * ND + (long)b * NS * ND + h * 64;
  const bf16* Vg  = vt + (long)z * 64 * NS;
  const bf16* QEg = qe + (long)z * NS * NS;

  #pragma unroll
  for (int i = 0; i < 2; ++i) {
    const int slot = i * 256 + tid;
    const int r = slot >> 3, seg = slot & 7;
    const int sc = (seg ^ (r & 7)) * 8;
    __builtin_amdgcn_global_load_lds(AS1(Qg + (long)r * ND + sc),
                                     AS3(Qlds + (i * 4096 + wid * 1024)), 16, 0, 0);
  }

  f32x4 aqk[8], apv[4];
  #pragma unroll
  for (int j = 0; j < 4; ++j) apv[j] = (f32x4){0.f, 0.f, 0.f, 0.f};
  float mrun[4] = {-3e38f, -3e38f, -3e38f, -3e38f};
  float lrun[4] = {0.f, 0.f, 0.f, 0.f};

  const int nk = (q0 + 191) >> 7;

  for (int kt = 0; kt < nk; ++kt) {
    const int k0 = kt * 128;
    __builtin_amdgcn_s_barrier();

    #pragma unroll
    for (int i = 0; i < 4; ++i) {
      const int slot = i * 256 + tid;
      const int r = slot >> 3, seg = slot & 7;
      const int sc = (seg ^ (r & 7)) * 8;
      __builtin_amdgcn_global_load_lds(AS1(Kg + (long)(k0 + r) * ND + sc),
                                       AS3(Klds + (i * 4096 + wid * 1024)), 16, 0, 0);
    }
    #pragma unroll
    for (int i = 0; i < 4; ++i) {
      const int slot = i * 256 + tid;
      const int d = slot >> 4, seg = slot & 15;
      const int sc = (seg ^ (d & 7)) * 8;
      __builtin_amdgcn_global_load_lds(AS1(Vg + (long)d * NS + k0 + sc),
                                       AS3(Vlds + (i * 4096 + wid * 1024)), 16, 0, 0);
    }

    unsigned short se[4][8];
    #pragma unroll
    for (int e = 0; e < 4; ++e) {
      const int qg = q0 + wid * 16 + g4 * 4 + e;
      const long rowb = (long)qg * NS;
      #pragma unroll
      for (int f = 0; f < 8; ++f) {
        int m = 1023 - qg + k0 + 16 * f + l15;
        m = m > 1023 ? 1023 : m;
        se[e][f] = *(const unsigned short*)(QEg + rowb + m);
      }
    }

    asm volatile("s_waitcnt vmcnt(0)" ::: "memory");
    __builtin_amdgcn_s_barrier();

    #pragma unroll
    for (int f = 0; f < 8; ++f) aqk[f] = (f32x4){0.f, 0.f, 0.f, 0.f};
    #pragma unroll
    for (int ds = 0; ds < 2; ++ds) {
      const int ko = (ds * 32 + g4 * 8) * 2;
      bf16x8 a = *(const bf16x8*)(Qlds + (((wid * 16 + l15) * 128 + ko) ^ xk));
      #pragma unroll
      for (int f = 0; f < 8; ++f) {
        bf16x8 bb = *(const bf16x8*)(Klds + (((16 * f + l15) * 128 + ko) ^ xk));
        aqk[f] = __builtin_amdgcn_mfma_f32_16x16x32_bf16(a, bb, aqk[f], 0, 0, 0);
      }
    }

    float ps[4][8];
    float scl[4];
    #pragma unroll
    for (int e = 0; e < 4; ++e) {
      const int qg = q0 + wid * 16 + g4 * 4 + e;
      float s[8];
      float mx = mrun[e];
      #pragma unroll
      for (int f = 0; f < 8; ++f) {
        const int kg = k0 + 16 * f + l15;
        const float sv = __uint_as_float((unsigned)se[e][f] << 16);
        const float t = (aqk[f][e] + sv) * 0.125f;
        s[f] = (kg <= qg) ? t : -1e30f;
        mx = fmaxf(mx, s[f]);
      }
      #pragma unroll
      for (int o = 1; o < 16; o <<= 1) mx = fmaxf(mx, __shfl_xor(mx, o));
      const float sc_ = __expf(mrun[e] - mx);
      float ls = 0.f;
      #pragma unroll
      for (int f = 0; f < 8; ++f) { const float p = __expf(s[f] - mx); ps[e][f] = p; ls += p; }
      #pragma unroll
      for (int o = 1; o < 16; o <<= 1) ls += __shfl_xor(ls, o);
      lrun[e] = lrun[e] * sc_ + ls;
      mrun[e] = mx;
      scl[e] = sc_;
    }
    #pragma unroll
    for (int fd = 0; fd < 4; ++fd)
      #pragma unroll
      for (int e = 0; e < 4; ++e) apv[fd][e] *= scl[e];

    #pragma unroll
    for (int e = 0; e < 4; ++e) {
      char* pr = Plds + (wid * 16 + g4 * 4 + e) * 272 + l15 * 2;
      #pragma unroll
      for (int f = 0; f < 8; ++f)
        *(bf16*)(pr + f * 32) = __float2bfloat16(ps[e][f]);
    }
    asm volatile("s_waitcnt lgkmcnt(0)" ::: "memory");
    __builtin_amdgcn_sched_barrier(0);

    #pragma unroll
    for (int ks = 0; ks < 4; ++ks) {
      const int ko = (ks * 32 + g4 * 8) * 2;
      bf16x8 a = *(const bf16x8*)(Plds + (wid * 16 + l15) * 272 + ko);
      #pragma unroll
      for (int fd = 0; fd < 4; ++fd) {
        bf16x8 bb = *(const bf16x8*)(Vlds + (((16 * fd + l15) * 256 + ko) ^ xk));
        apv[fd] = __builtin_amdgcn_mfma_f32_16x16x32_bf16(a, bb, apv[fd], 0, 0, 0);
      }
    }
  }

  #pragma unroll
  for (int e = 0; e < 4; ++e) {
    const float rl = 1.f / lrun[e];
    const int qg = q0 + wid * 16 + g4 * 4 + e;
    bf16* orow = ob + ((long)b * NS + qg) * ND + h * 64;
    #pragma unroll
    for (int fd = 0; fd < 4; ++fd)
      orow[16 * fd + l15] = __float2bfloat16(apv[fd][e] * rl);
  }
}

// ------ vectorized transpose+convert: in f32 (R x C) -> out bf16 (C x R) ------
__global__ void transpose64_k(const float* __restrict__ in, bf16* __restrict__ out,
                              int R, int C, long inZ, long outZ) {
  __shared__ float t[64][65];
  const float* ip = in + (long)blockIdx.z * inZ;
  bf16* op = out + (long)blockIdx.z * outZ;
  const int c0 = blockIdx.x * 64, r0 = blockIdx.y * 64;
  const int tid = threadIdx.x;
  const int lr = tid >> 4;
  const int lc = (tid & 15) * 4;
  #pragma unroll
  for (int i = 0; i < 4; ++i) {
    const float4 v = *(const float4*)(ip + (long)(r0 + lr + 16 * i) * C + c0 + lc);
    t[lr + 16 * i][lc]     = v.x;
    t[lr + 16 * i][lc + 1] = v.y;
    t[lr + 16 * i][lc + 2] = v.z;
    t[lr + 16 * i][lc + 3] = v.w;
  }
  __syncthreads();
  #pragma unroll
  for (int i = 0; i < 4; ++i) {
    const int oc = lr + 16 * i;
    ushort4 u;
    bf16 h0 = __float2bfloat16(t[lc][oc]);
    bf16 h1 = __float2bfloat16(t[lc + 1][oc]);
    bf16 h2 = __float2bfloat16(t[lc + 2][oc]);
    bf16 h3 = __float2bfloat16(t[lc + 3][oc]);
    u.x = *(unsigned short*)&h0; u.y = *(unsigned short*)&h1;
    u.z = *(unsigned short*)&h2; u.w = *(unsigned short*)&h3;
    *(ushort4*)(op + (long)(c0 + oc) * R + r0 + lc) = u;
  }
}

// v (B,S,D) -> vt (B,H,Dh,S)
__global__ void transpose_v_k(const bf16* __restrict__ v, bf16* __restrict__ vt) {
  __shared__ bf16 t[32][33];
  const int z = blockIdx.z, b = z >> 4, h = z & 15;
  const bf16* ip = v + (long)b * NS * ND + h * 64;
  bf16* op = vt + (long)z * 64 * NS;
  const int s0 = blockIdx.x * 32, d0 = blockIdx.y * 32;
  const int tx = threadIdx.x, ty = threadIdx.y;
  #pragma unroll
  for (int i = 0; i < 4; ++i)
    t[ty * 4 + i][tx] = ip[(long)(s0 + ty * 4 + i) * ND + d0 + tx];
  __syncthreads();
  #pragma unroll
  for (int i = 0; i < 4; ++i)
    op[(long)(d0 + ty * 4 + i) * NS + s0 + tx] = t[tx][ty * 4 + i];
}

__global__ void cvt_bf16_k(const float* __restrict__ in, bf16* __restrict__ out, int n) {
  int i = blockIdx.x * 256 + threadIdx.x;
  if (i < n) out[i] = __float2bfloat16(in[i]);
}

__global__ void pack3_k(const float* __restrict__ a, const float* __restrict__ b,
                        const float* __restrict__ c, float* __restrict__ out) {
  int i = blockIdx.x * 256 + threadIdx.x;
  if (i >= NL * 3 * ND) return;
  int d = i % ND, r = (i / ND) % 3, l = i / (3 * ND);
  const float* src = (r == 0) ? a : ((r == 1) ? b : c);
  out[i] = src[l * ND + d];
}

__global__ void embed_k(const int* __restrict__ tok, const float* __restrict__ emb,
                        float* __restrict__ x, bf16* __restrict__ xb) {
  const int row = blockIdx.x;
  const int t = tok[row];
  const float4 val = ((const float4*)(emb + (long)t * ND))[threadIdx.x];
  ((float4*)(x + (long)row * ND))[threadIdx.x] = val;
  bf16* xp = xb + (long)row * ND + threadIdx.x * 4;
  xp[0] = __float2bfloat16(val.x); xp[1] = __float2bfloat16(val.y);
  xp[2] = __float2bfloat16(val.z); xp[3] = __float2bfloat16(val.w);
}

// x = LN(x + g0+g1+g2+g3) * s + b (in place on x), also emit xb = bf16(x)
__global__ void resid_ln_k(float* __restrict__ x, const float* __restrict__ g,
                           long gs,
                           const float* __restrict__ s, const float* __restrict__ b,
                           bf16* __restrict__ xb) {
  const int row = blockIdx.x, tid = threadIdx.x;
  const float4 xv = ((const float4*)(x + (long)row * ND))[tid];
  const float4 ga = ((const float4*)(g + (long)row * ND))[tid];
  const float4 gb = ((const float4*)(g + gs + (long)row * ND))[tid];
  const float4 gc = ((const float4*)(g + 2 * gs + (long)row * ND))[tid];
  const float4 gd = ((const float4*)(g + 3 * gs + (long)row * ND))[tid];
  float h0 = xv.x + ga.x + gb.x + gc.x + gd.x;
  float h1 = xv.y + ga.y + gb.y + gc.y + gd.y;
  float h2 = xv.z + ga.z + gb.z + gc.z + gd.z;
  float h3 = xv.w + ga.w + gb.w + gc.w + gd.w;
  float ls = h0 + h1 + h2 + h3;
  __shared__ float red[8];
  #pragma unroll
  for (int o = 32; o; o >>= 1) ls += __shfl_xor(ls, o);
  const int lane = tid & 63, wid = tid >> 6;
  if (lane == 0) red[wid] = ls;
  __syncthreads();
  const float mu = (red[0] + red[1] + red[2] + red[3]) * (1.f / ND);
  const float d0 = h0 - mu, d1 = h1 - mu, d2 = h2 - mu, d3 = h3 - mu;
  float lv = d0 * d0 + d1 * d1 + d2 * d2 + d3 * d3;
  #pragma unroll
  for (int o = 32; o; o >>= 1) lv += __shfl_xor(lv, o);
  if (lane == 0) red[4 + wid] = lv;
  __syncthreads();
  const float rs = rsqrtf((red[4] + red[5] + red[6] + red[7]) * (1.f / ND) + 1e-5f);
  const float4 sv = ((const float4*)s)[tid];
  const float4 bv = ((const float4*)b)[tid];
  const float y0 = d0 * rs * sv.x + bv.x, y1 = d1 * rs * sv.y + bv.y;
  const float y2 = d2 * rs * sv.z + bv.z, y3 = d3 * rs * sv.w + bv.w;
  ((float4*)(x + (long)row * ND))[tid] = make_float4(y0, y1, y2, y3);
  bf16* xp = xb + (long)row * ND + tid * 4;
  xp[0] = __float2bfloat16(y0); xp[1] = __float2bfloat16(y1);
  xp[2] = __float2bfloat16(y2); xp[3] = __float2bfloat16(y3);
}

extern "C" void kernel_launch(void* const* d_in, const int* in_sizes, int n_in,
                              void* d_out, int out_size, void* d_ws, size_t ws_size,
                              hipStream_t stream) {
  const int*   tokens = (const int*)d_in[0];
  const float* emb  = (const float*)d_in[1];
  const float* Wq   = (const float*)d_in[2];
  const float* bq   = (const float*)d_in[3];
  const float* Wk   = (const float*)d_in[4];
  const float* bk   = (const float*)d_in[5];
  const float* Wv   = (const float*)d_in[6];
  const float* bv   = (const float*)d_in[7];
  const float* Wo   = (const float*)d_in[8];
  const float* bo   = (const float*)d_in[9];
  const float* rpe  = (const float*)d_in[10];
  const float* ln1s = (const float*)d_in[11];
  const float* ln1b = (const float*)d_in[12];
  const float* ln2s = (const float*)d_in[13];
  const float* ln2b = (const float*)d_in[14];
  const float* W1   = (const float*)d_in[15];
  const float* b1   = (const float*)d_in[16];
  const float* W2   = (const float*)d_in[17];
  const float* b2   = (const float*)d_in[18];
  const float* Wout = (const float*)d_in[19];
  const float* bout = (const float*)d_in[20];
  float* out = (float*)d_out;

  char* wsb = (char*)d_ws;
  size_t off = 0;
  auto take = [&](size_t bytes) -> void* {
    void* r = wsb + off;
    off = (off + bytes + 255) & ~(size_t)255;
    return r;
  };
  bf16*  wqkvT = (bf16*)take((size_t)NL * 3 * ND * ND * 2);
  bf16*  woT   = (bf16*)take((size_t)NL * ND * ND * 2);
  bf16*  w1T   = (bf16*)take((size_t)NL * NF * ND * 2);
  bf16*  w2T   = (bf16*)take((size_t)NL * ND * NF * 2);
  bf16*  woutT = (bf16*)take((size_t)NV * ND * 2);
  bf16*  rpeb  = (bf16*)take((size_t)NL * NS * NDH * 2);
  float* qkvb  = (float*)take((size_t)NL * 3 * ND * 4);
  float* x     = (float*)take((size_t)NB * NS * ND * 4);
  bf16*  xb    = (bf16*)take((size_t)NB * NS * ND * 2);
  bf16*  qkv   = (bf16*)take((size_t)3 * NB * NS * ND * 2);
  bf16*  vt    = (bf16*)take((size_t)NB * NS * ND * 2);
  bf16*  ob    = (bf16*)take((size_t)NB * NS * ND * 2);
  float* g     = (float*)take((size_t)4 * NB * NS * ND * 4);  // split-K partials g0..g3
  bf16*  hbuf  = (bf16*)take((size_t)NB * NS * NF * 2);
  bf16*  qe    = (bf16*)take((size_t)NB * NH * NS * NS * 2 + 4096);
  (void)in_sizes; (void)n_in; (void)out_size; (void)ws_size;

  const long gStride = (long)NB * NS * ND;

  transpose64_k<<<dim3(ND/64, ND/64, NL), 256, 0, stream>>>(Wq, wqkvT,                   ND, ND, (long)ND*ND, (long)3*ND*ND);
  transpose64_k<<<dim3(ND/64, ND/64, NL), 256, 0, stream>>>(Wk, wqkvT + (size_t)ND*ND,   ND, ND, (long)ND*ND, (long)3*ND*ND);
  transpose64_k<<<dim3(ND/64, ND/64, NL), 256, 0, stream>>>(Wv, wqkvT + (size_t)2*ND*ND, ND, ND, (long)ND*ND, (long)3*ND*ND);
  transpose64_k<<<dim3(ND/64, ND/64, NL), 256, 0, stream>>>(Wo, woT,                     ND, ND, (long)ND*ND, (long)ND*ND);
  transpose64_k<<<dim3(NF/64, ND/64, NL), 256, 0, stream>>>(W1, w1T,                     ND, NF, (long)ND*NF, (long)NF*ND);
  transpose64_k<<<dim3(ND/64, NF/64, NL), 256, 0, stream>>>(W2, w2T,                     NF, ND, (long)NF*ND, (long)ND*NF);
  transpose64_k<<<dim3(NV/64, ND/64, 1),  256, 0, stream>>>(Wout, woutT,                 ND, NV, 0, 0);
  cvt_bf16_k<<<(NL*NS*NDH + 255)/256, 256, 0, stream>>>(rpe, rpeb, NL*NS*NDH);
  pack3_k<<<(NL*3*ND + 255)/256, 256, 0, stream>>>(bq, bk, bv, qkvb);
  embed_k<<<NB*NS, 256, 0, stream>>>(tokens, emb, x, xb);

  const dim3 tb(32, 8);
  for (int l = 0; l < NL; ++l) {
    // QKV fused (N=3072), slab-scatter epilogue
    gemm128_bt<3, true, 1><<<dim3(3*ND/256, NB*NS/128), 256, 0, stream>>>(
        xb, wqkvT + (size_t)l*3*ND*ND, qkv, qkvb + (size_t)l*3*ND,
        ND, ND, ND, ND, gStride);
    transpose_v_k<<<dim3(NS/32, 2, NB*NH), tb, 0, stream>>>(qkv + (size_t)2*NB*NS*ND, vt);
    // Q @ E^T -> qe[z][q][m] (bf16, m-space; only live band written)
    gemm_bt<128, 1, 3, false, 0, 0><<<dim3(NS/128, NS/128, NB*NH), 256, 0, stream>>>(
        qkv, rpeb + (size_t)l*NS*NDH, qe, nullptr,
        NS, NS, NDH, ND, NDH, NS, NH,
        (long)NS*ND, 64, 0, 0, (long)NH*NS*NS, (long)NS*NS, 0);
    flash_attn_k<<<dim3(NB*NH, 16), 256, 0, stream>>>(qkv, vt, qe, ob);
    // O projection, split-K x4 -> g0..g3 (f32; bias on z==0); 256 blocks
    gemm128_bt<0, true, 4><<<dim3(ND/256, NB*NS/128, 4), 256, 0, stream>>>(
        ob, woT + (size_t)l*ND*ND, g, bo + (size_t)l*ND, ND, ND, ND, ND, gStride);
    resid_ln_k<<<NB*NS, 256, 0, stream>>>(x, g, gStride,
        ln1s + (size_t)l*ND, ln1b + (size_t)l*ND, xb);
    // FFN1, bias + GELU, bf16 out (256 blocks)
    gemm128_bt<2, true, 1><<<dim3(NF/256, NB*NS/128), 256, 0, stream>>>(
        xb, w1T + (size_t)l*NF*ND, hbuf, b1 + (size_t)l*NF, ND, ND, ND, NF, 0);
    // FFN2, split-K x4 (K=4096 -> 4x1024) -> g0..g3; 256 blocks
    gemm128_bt<0, true, 4><<<dim3(ND/256, NB*NS/128, 4), 256, 0, stream>>>(
        hbuf, w2T + (size_t)l*ND*NF, g, b2 + (size_t)l*ND, NF, NF, NF, ND, gStride);
    resid_ln_k<<<NB*NS, 256, 0, stream>>>(x, g, gStride,
        ln2s + (size_t)l*ND, ln2b + (size_t)l*ND, xb);
  }
  // final vocab projection: 8-phase 256x256 kernel (1000 blocks), f32 out + bias
  gemm256p<0, true><<<dim3(NV/256, NB*NS/256), 512, 0, stream>>>(
      xb, woutT, out, bout, ND, ND, ND, NV);
}

// Round 10
// 1354.934 us; speedup vs baseline: 1.9943x; 1.0022x over previous
//
#include <hip/hip_runtime.h>
#include <hip/hip_bf16.h>
#include <cstdint>

constexpr int NB = 2, NS = 1024, ND = 1024, NH = 16, NL = 6, NV = 32000, NF = 4096, NDH = 64;

using bf16 = __hip_bfloat16;
typedef __bf16 bf16x8 __attribute__((ext_vector_type(8)));
typedef float f32x4 __attribute__((ext_vector_type(4)));

#define AS1(p) ((const __attribute__((address_space(1))) void*)(p))
#define AS3(p) ((__attribute__((address_space(3))) void*)(p))

__device__ __forceinline__ float gelu_f(float x) {
  float z = 1.5957691216057308f * (x + 0.044715f * x * x * x);
  return x / (1.f + __expf(-z));
}

// ========== 256x256 PAIR-pipelined GEMM (1 barrier / 32-MFMA pair) ==========
// 8 waves. K split into 32-wide chunks; chunk p uses plane-set s=p&3
// (A 16KB + B 16KB at s*32768). Per pair: vmcnt(8) -> barrier -> 12 ds_read
// (issue-pinned) -> stage chunk p+3 -> lgkmcnt(4) -> 16 MFMA -> lgkmcnt(0)
// -> 16 MFMA. Uniform vmcnt(8) steady (3 chunk-stages in flight); drain
// 8/4/0 in last 3 pairs. Single barrier/pair is race-free: a wave's reads
// complete before its MFMAs issue -> before it reaches the next barrier ->
// stages issued after that barrier cannot overwrite live data.
// Requires M%256==0, N%256==0, K%32==0, K/32>=4, nwg%8==0.
template<int EP, bool HASBIAS>
__global__ __launch_bounds__(512)
void gemm256p(const bf16* __restrict__ A, const bf16* __restrict__ Bt,
              void* __restrict__ Cv, const float* __restrict__ bias,
              int K, int lda, int ldb, int ldc)
{
  const int nM = gridDim.y, nN = gridDim.x;
  const int nwg = nM * nN;
  const int bid = blockIdx.y * nN + blockIdx.x;
  const int wg = (bid & 7) * (nwg >> 3) + (bid >> 3);
  const int m0 = (wg % nM) * 256;
  const int n0 = (wg / nM) * 256;

  __shared__ char lds[131072];   // set s at s*32768: A-plane 16K, B-plane 16K

  const int tid = threadIdx.x, lane = tid & 63, wid = tid >> 6;
  const int wm = (wid >> 2) * 128;   // 2 M-waves x 4 N-waves
  const int wn = (wid & 3) * 64;
  const int l15 = lane & 15, g4 = lane >> 4;
  const int rdk = (g4 * 16) ^ ((l15 >> 3) << 5);

  const int srow = wid * 16 + (lane >> 2);
  const int scol = ((lane & 3) * 8) ^ (((lane >> 5) & 1) << 4);
  const bf16* gA = A  + (long)(m0 + srow) * lda + scol;
  const bf16* gB = Bt + (long)(n0 + srow) * ldb + scol;
  const long a128 = 128l * lda, b128 = 128l * ldb;

  f32x4 acc[8][4] = {};
  const int NP = K >> 5;   // 32-k chunks

#define STGP(p_) do {                                                                  \
    const int s_ = (p_) & 3; const long ko_ = (long)(p_) * 32;                         \
    char* dA = lds + s_ * 32768 + wid * 1024;                                          \
    char* dB = dA + 16384;                                                             \
    __builtin_amdgcn_global_load_lds(AS1(gA + ko_),        AS3(dA),        16, 0, 0);  \
    __builtin_amdgcn_global_load_lds(AS1(gA + ko_ + a128), AS3(dA + 8192), 16, 0, 0);  \
    __builtin_amdgcn_global_load_lds(AS1(gB + ko_),        AS3(dB),        16, 0, 0);  \
    __builtin_amdgcn_global_load_lds(AS1(gB + ko_ + b128), AS3(dB + 8192), 16, 0, 0);  \
  } while (0)

#define PAIR(vm_, p_, DOSTG_) do {                                                     \
    asm volatile("s_waitcnt vmcnt(" #vm_ ")" ::: "memory");                            \
    __builtin_amdgcn_s_barrier();                                                      \
    asm volatile("" ::: "memory");                                                     \
    const char* la_ = lds + ((p_) & 3) * 32768;                                        \
    const char* lb_ = la_ + 16384;                                                     \
    bf16x8 bfr[4], af[8];                                                              \
    _Pragma("unroll") for (int j_ = 0; j_ < 4; ++j_)                                   \
      bfr[j_] = *(const bf16x8*)(lb_ + (wn + j_ * 16 + l15) * 64 + rdk);               \
    _Pragma("unroll") for (int i_ = 0; i_ < 4; ++i_)                                   \
      af[i_] = *(const bf16x8*)(la_ + (wm + i_ * 16 + l15) * 64 + rdk);                \
    __builtin_amdgcn_sched_barrier(0);                                                 \
    _Pragma("unroll") for (int i_ = 4; i_ < 8; ++i_)                                   \
      af[i_] = *(const bf16x8*)(la_ + (wm + i_ * 16 + l15) * 64 + rdk);                \
    if (DOSTG_) STGP((p_) + 3);                                                        \
    asm volatile("s_waitcnt lgkmcnt(4)" ::: "memory");                                 \
    __builtin_amdgcn_sched_barrier(0);                                                 \
    __builtin_amdgcn_s_setprio(1);                                                     \
    _Pragma("unroll") for (int i_ = 0; i_ < 4; ++i_)                                   \
      _Pragma("unroll") for (int j_ = 0; j_ < 4; ++j_)                                 \
        acc[i_][j_] = __builtin_amdgcn_mfma_f32_16x16x32_bf16(af[i_], bfr[j_], acc[i_][j_], 0, 0, 0); \
    __builtin_amdgcn_s_setprio(0);                                                     \
    asm volatile("s_waitcnt lgkmcnt(0)" ::: "memory");                                 \
    __builtin_amdgcn_sched_barrier(0);                                                 \
    __builtin_amdgcn_s_setprio(1);                                                     \
    _Pragma("unroll") for (int i_ = 4; i_ < 8; ++i_)                                   \
      _Pragma("unroll") for (int j_ = 0; j_ < 4; ++j_)                                 \
        acc[i_][j_] = __builtin_amdgcn_mfma_f32_16x16x32_bf16(af[i_], bfr[j_], acc[i_][j_], 0, 0, 0); \
    __builtin_amdgcn_s_setprio(0);                                                     \
  } while (0)

  STGP(0); STGP(1); STGP(2);
  for (int p = 0; p < NP - 3; ++p) PAIR(8, p, 1);
  PAIR(8, NP - 3, 0);
  PAIR(4, NP - 2, 0);
  PAIR(0, NP - 1, 0);
#undef PAIR
#undef STGP

  const int rq = (lane >> 4) * 4;
  #pragma unroll
  for (int i = 0; i < 8; ++i) {
    const int r0 = m0 + wm + i * 16 + rq;
    #pragma unroll
    for (int j = 0; j < 4; ++j) {
      const int c = n0 + wn + j * 16 + l15;
      float bv = 0.f;
      if constexpr (HASBIAS) bv = bias[c];
      #pragma unroll
      for (int e = 0; e < 4; ++e) {
        float v = acc[i][j][e] + bv;
        if constexpr (EP == 2) v = gelu_f(v);
        if constexpr (EP == 0) ((float*)Cv)[(long)(r0 + e) * ldc + c] = v;
        else                   ((bf16*)Cv)[(long)(r0 + e) * ldc + c] = __float2bfloat16(v);
      }
    }
  }
}

// ============ 128x256 deep-pipelined GEMM, 4 waves, 2 blocks/CU =============
template<int EP, bool HASBIAS, int KSZ>
__global__ __launch_bounds__(256)
void gemm128_bt(const bf16* __restrict__ A, const bf16* __restrict__ Bt,
                void* __restrict__ Cv, const float* __restrict__ bias,
                int K, int lda, int ldb, int ldc, long sEP)
{
  const int nM = gridDim.y, nN = gridDim.x;
  const int nwg = nM * nN;
  const int bid = blockIdx.y * nN + blockIdx.x;
  const int qq = nwg >> 3;
  const int wg = (bid & 7) * qq + (bid >> 3);
  const int m0 = (wg % nM) * 128;
  const int n0 = (wg / nM) * 256;

  const int kLen = K / KSZ;
  const long kOff = (long)blockIdx.z * kLen;

  __shared__ char lds[73728];

  const int tid  = threadIdx.x;
  const int lane = tid & 63;
  const int wid  = tid >> 6;
  const int wn   = wid * 64;
  const int l15  = lane & 15;
  const int rdk  = ((lane >> 4) * 16) ^ ((l15 >> 3) << 5);

  const int srow = wid * 16 + (lane >> 2);
  const int scol = ((lane & 3) * 8) ^ (((lane >> 5) & 1) << 4);
  const bf16* gA = A  + (long)(m0 + srow) * lda + scol + kOff;
  const bf16* gB = Bt + (long)(n0 + srow) * ldb + scol + kOff;
  const long a64 = 64l * lda, b64 = 64l * ldb;

  f32x4 acc[8][4] = {};
  const int NT = kLen >> 5;

#define STG(t_, b_) do {                                                               \
    char* dA = lds + (b_) * 24576 + wid * 1024;                                        \
    char* dB = lds + (b_) * 24576 + 8192 + wid * 1024;                                 \
    const long ko_ = (long)(t_) * 32;                                                  \
    __builtin_amdgcn_global_load_lds(AS1(gA + ko_),           AS3(dA),         16, 0, 0); \
    __builtin_amdgcn_global_load_lds(AS1(gA + ko_ + a64),     AS3(dA + 4096),  16, 0, 0); \
    __builtin_amdgcn_global_load_lds(AS1(gB + ko_),           AS3(dB),         16, 0, 0); \
    __builtin_amdgcn_global_load_lds(AS1(gB + ko_ + b64),     AS3(dB + 4096),  16, 0, 0); \
    __builtin_amdgcn_global_load_lds(AS1(gB + ko_ + 2 * b64), AS3(dB + 8192),  16, 0, 0); \
    __builtin_amdgcn_global_load_lds(AS1(gB + ko_ + 3 * b64), AS3(dB + 12288), 16, 0, 0); \
  } while (0)

#define TBODY(cur_) do {                                                               \
    const char* la_ = lds + (cur_) * 24576;                                            \
    const char* lb_ = la_ + 8192;                                                      \
    bf16x8 bf_[4], af_[8];                                                             \
    _Pragma("unroll") for (int j_ = 0; j_ < 4; ++j_)                                   \
      bf_[j_] = *(const bf16x8*)(lb_ + (wn + j_ * 16 + l15) * 64 + rdk);               \
    _Pragma("unroll") for (int i_ = 0; i_ < 8; ++i_)                                   \
      af_[i_] = *(const bf16x8*)(la_ + (i_ * 16 + l15) * 64 + rdk);                    \
    __builtin_amdgcn_s_setprio(1);                                                     \
    _Pragma("unroll") for (int i_ = 0; i_ < 8; ++i_)                                   \
      _Pragma("unroll") for (int j_ = 0; j_ < 4; ++j_)                                 \
        acc[i_][j_] = __builtin_amdgcn_mfma_f32_16x16x32_bf16(af_[i_], bf_[j_], acc[i_][j_], 0, 0, 0); \
    __builtin_amdgcn_s_setprio(0);                                                     \
  } while (0)

  STG(0, 0); STG(1, 1);
  int cur = 0, nxt = 2;
  for (int t = 0; t < NT - 1; ++t) {
    asm volatile("s_waitcnt vmcnt(6)" ::: "memory");
    __builtin_amdgcn_s_barrier();
    asm volatile("" ::: "memory");
    if (t + 2 < NT) STG(t + 2, nxt);
    TBODY(cur);
    cur = (cur == 2) ? 0 : cur + 1;
    nxt = (nxt == 2) ? 0 : nxt + 1;
  }
  asm volatile("s_waitcnt vmcnt(0)" ::: "memory");
  __builtin_amdgcn_s_barrier();
  asm volatile("" ::: "memory");
  TBODY(cur);
#undef TBODY
#undef STG

  const int rq = (lane >> 4) * 4;
  #pragma unroll
  for (int i = 0; i < 8; ++i) {
    const int r0 = m0 + i * 16 + rq;
    #pragma unroll
    for (int j = 0; j < 4; ++j) {
      const int c = n0 + wn + j * 16 + l15;
      float bv = 0.f;
      if constexpr (HASBIAS) { if (KSZ == 1 || blockIdx.z == 0) bv = bias[c]; }
      #pragma unroll
      for (int e = 0; e < 4; ++e) {
        float v = acc[i][j][e] + bv;
        if constexpr (EP == 0) {
          float* Cz = (float*)Cv + (KSZ > 1 ? (long)blockIdx.z * sEP : 0);
          Cz[(long)(r0 + e) * ldc + c] = v;
        } else if constexpr (EP == 2) {
          ((bf16*)Cv)[(long)(r0 + e) * ldc + c] = __float2bfloat16(gelu_f(v));
        } else {           // EP==3: qkv slab scatter
          ((bf16*)Cv)[(long)(c >> 10) * sEP + (long)(r0 + e) * ND + (c & 1023)] =
              __float2bfloat16(v);
        }
      }
    }
  }
}

// ---------------- gemm_bt (QE only): C=A@Bt^T, CZ=3 band skip, bf16 out -----
template<int BN, int EP, int CZ, bool HASBIAS, int SWZ, int KS>
__global__ __launch_bounds__(256)
void gemm_bt(const bf16* __restrict__ A, const bf16* __restrict__ Bt,
             void* __restrict__ Cv, const float* __restrict__ bias,
             int M, int N, int K, int lda, int ldb, int ldc, int ZH,
             long sAb, long sAh, long sBb, long sBh, long sCb, long sCh, long sBias)
{
  constexpr int BM = 128, BK = 32;
  constexpr int WGN = (BN == 128) ? 2 : 1;
  constexpr int FM  = (BM / (4 / WGN)) / 16;
  constexpr int FN  = (BN / WGN) / 16;

  const int z  = blockIdx.z;
  const int zb = z / ZH, zh = z % ZH;
  const bf16* Ab = A + (long)zb * sAb + (long)zh * sAh;
  const bf16* Bb = Bt + (long)zb * sBb + (long)zh * sBh;

  const int m0 = blockIdx.y * BM;
  const int n0 = blockIdx.x * BN;

  if constexpr (CZ == 3) { if (m0 + n0 + BM + BN - 2 < NS - 1) return; }

  __shared__ bf16 Asm[BM * BK];
  __shared__ bf16 Bsm[BN * BK];

  const int tid  = threadIdx.x;
  const int lane = tid & 63;
  const int wid  = tid >> 6;
  const int wm = (wid / WGN) * (FM * 16);
  const int wn = (wid % WGN) * (FN * 16);
  const int l15 = lane & 15;
  const int lk8 = (lane >> 4) * 8;

  f32x4 acc[FM][FN] = {};

  const int srow = tid >> 2;
  const int scol = (tid & 3) * 8;
  const bf16* gA = Ab + (long)(m0 + srow) * lda + scol;
  const bf16* gB = Bb + (long)(n0 + srow) * ldb + scol;
  bf16* ldsA = Asm + wid * 512;
  bf16* ldsB = Bsm + wid * 512;

  for (int k0 = 0; k0 < K; k0 += BK) {
    __builtin_amdgcn_global_load_lds(AS1(gA + k0), AS3(ldsA), 16, 0, 0);
    __builtin_amdgcn_global_load_lds(AS1(gA + 64l * lda + k0), AS3(ldsA + 2048), 16, 0, 0);
    __builtin_amdgcn_global_load_lds(AS1(gB + k0), AS3(ldsB), 16, 0, 0);
    if constexpr (BN == 128)
      __builtin_amdgcn_global_load_lds(AS1(gB + 64l * ldb + k0), AS3(ldsB + 2048), 16, 0, 0);
    asm volatile("s_waitcnt vmcnt(0)" ::: "memory");
    __syncthreads();

    bf16x8 af[FM], bfr[FN];
    #pragma unroll
    for (int i = 0; i < FM; ++i)
      af[i] = *reinterpret_cast<const bf16x8*>(&Asm[(wm + i * 16 + l15) * BK + lk8]);
    #pragma unroll
    for (int j = 0; j < FN; ++j)
      bfr[j] = *reinterpret_cast<const bf16x8*>(&Bsm[(wn + j * 16 + l15) * BK + lk8]);
    #pragma unroll
    for (int i = 0; i < FM; ++i)
      #pragma unroll
      for (int j = 0; j < FN; ++j)
        acc[i][j] = __builtin_amdgcn_mfma_f32_16x16x32_bf16(af[i], bfr[j], acc[i][j], 0, 0, 0);
    __syncthreads();
  }

  const int rq = (lane >> 4) * 4;
  const long cb = (long)zb * sCb + (long)zh * sCh;
  #pragma unroll
  for (int i = 0; i < FM; ++i) {
    const int r0 = m0 + wm + i * 16 + rq;
    #pragma unroll
    for (int j = 0; j < FN; ++j) {
      const int c = n0 + wn + j * 16 + l15;
      float bv = 0.f;
      if constexpr (HASBIAS) bv = bias[(long)zb * sBias + c];
      #pragma unroll
      for (int e = 0; e < 4; ++e) {
        float v = acc[i][j][e] + bv;
        const long idx = cb + (long)(r0 + e) * ldc + c;
        if constexpr (EP == 0) ((float*)Cv)[idx] = v;
        else                   ((bf16*)Cv)[idx] = __float2bfloat16(v);
      }
    }
  }
}

// ======= fused flash attention, T14 reg-prefetch of K/V, Q in registers =====
// Per k-tile: barrier -> ds_write K/V (swizzled scatter, from regs loaded
// last tile) -> srel loads -> prefetch next K/V to regs -> lgkmcnt(0) ->
// barrier -> QK MFMA -> online softmax -> P to LDS -> PV MFMA.
__global__ __launch_bounds__(256)
void flash_attn_k(const bf16* __restrict__ qkv, const bf16* __restrict__ vt,
                  const bf16* __restrict__ qe, bf16* __restrict__ ob)
{
  const int z  = blockIdx.x;
  const int qt = 15 - blockIdx.y;
  const int b  = z >> 4, h = z & 15;
  const int q0 = qt * 64;
  const int tid  = threadIdx.x;
  const int lane = tid & 63;
  const int wid  = tid >> 6;
  const int l15  = lane & 15;
  const int g4   = lane >> 4;
  const int xk   = (l15 & 7) << 4;

  __shared__ char lds[50176];
  char* Klds = lds;                    // [128][128B] swizzled
  char* Vlds = lds + 16384;            // [64][256B]  swizzled
  char* Plds = lds + 32768;            // [64][272B]

  const bf16* Kg  = qkv + (long)NB * NS * ND + (long)b * NS * ND + h * 64;
  const bf16* Vg  = vt + (long)z * 64 * NS;
  const bf16* QEg = qe + (long)z * NS * NS;

  // Q fragments live in registers (rows q0+wid*16+l15, k-cols ds*32+g4*8)
  const bf16* Qrow = qkv + ((long)b * NS + q0 + wid * 16 + l15) * ND + h * 64 + g4 * 8;
  const bf16x8 qr0 = *(const bf16x8*)(Qrow);
  const bf16x8 qr1 = *(const bf16x8*)(Qrow + 32);

  // staging geometry: K slot i -> row i*32 + (tid>>3), seg tid&7
  //                   V slot i -> row i*16 + (tid>>4), seg tid&15
  const int kR = tid >> 3, kSeg = tid & 7;
  const int vD = tid >> 4, vSeg = tid & 15;
  int wKa[4], wVa[4];
  #pragma unroll
  for (int i = 0; i < 4; ++i) {
    const int r = i * 32 + kR;
    wKa[i] = (r * 128 + kSeg * 16) ^ ((r & 7) << 4);
    const int d = i * 16 + vD;
    wVa[i] = (d * 256 + vSeg * 16) ^ ((d & 7) << 4);
  }

  f32x4 aqk[8], apv[4];
  #pragma unroll
  for (int j = 0; j < 4; ++j) apv[j] = (f32x4){0.f, 0.f, 0.f, 0.f};
  float mrun[4] = {-3e38f, -3e38f, -3e38f, -3e38f};
  float lrun[4] = {0.f, 0.f, 0.f, 0.f};

  const int nk = (q0 + 191) >> 7;

  // prologue: tile 0 K/V -> registers
  bf16x8 kr[4], vr[4];
  #pragma unroll
  for (int i = 0; i < 4; ++i) {
    kr[i] = *(const bf16x8*)(Kg + (long)(i * 32 + kR) * ND + kSeg * 8);
    vr[i] = *(const bf16x8*)(Vg + (long)(i * 16 + vD) * NS + vSeg * 8);
  }

  for (int kt = 0; kt < nk; ++kt) {
    const int k0 = kt * 128;
    __builtin_amdgcn_s_barrier();      // all waves done reading prev K/V tile

    #pragma unroll
    for (int i = 0; i < 4; ++i) *(bf16x8*)(Klds + wKa[i]) = kr[i];
    #pragma unroll
    for (int i = 0; i < 4; ++i) *(bf16x8*)(Vlds + wVa[i]) = vr[i];

    // srel loads FIRST (their vmcnt-wait must not drain the prefetch)
    unsigned short se[4][8];
    #pragma unroll
    for (int e = 0; e < 4; ++e) {
      const int qg = q0 + wid * 16 + g4 * 4 + e;
      const long rowb = (long)qg * NS;
      #pragma unroll
      for (int f = 0; f < 8; ++f) {
        int m = 1023 - qg + k0 + 16 * f + l15;
        m = m > 1023 ? 1023 : m;
        se[e][f] = *(const unsigned short*)(QEg + rowb + m);
      }
    }
    __builtin_amdgcn_sched_barrier(0);
    // prefetch next K/V tile into registers (hidden under this tile's compute)
    if (kt + 1 < nk) {
      const int k1 = k0 + 128;
      #pragma unroll
      for (int i = 0; i < 4; ++i) {
        kr[i] = *(const bf16x8*)(Kg + (long)(k1 + i * 32 + kR) * ND + kSeg * 8);
        vr[i] = *(const bf16x8*)(Vg + (long)(i * 16 + vD) * NS + k1 + vSeg * 8);
      }
    }
    asm volatile("s_waitcnt lgkmcnt(0)" ::: "memory");   // my ds_writes committed
    __builtin_amdgcn_sched_barrier(0);
    __builtin_amdgcn_s_barrier();      // all waves' K/V visible

    // ---- QK^T
    #pragma unroll
    for (int f = 0; f < 8; ++f) aqk[f] = (f32x4){0.f, 0.f, 0.f, 0.f};
    {
      const int ko0 = g4 * 16;
      #pragma unroll
      for (int f = 0; f < 8; ++f) {
        bf16x8 bb = *(const bf16x8*)(Klds + (((16 * f + l15) * 128 + ko0) ^ xk));
        aqk[f] = __builtin_amdgcn_mfma_f32_16x16x32_bf16(qr0, bb, aqk[f], 0, 0, 0);
      }
      const int ko1 = 64 + g4 * 16;
      #pragma unroll
      for (int f = 0; f < 8; ++f) {
        bf16x8 bb = *(const bf16x8*)(Klds + (((16 * f + l15) * 128 + ko1) ^ xk));
        aqk[f] = __builtin_amdgcn_mfma_f32_16x16x32_bf16(qr1, bb, aqk[f], 0, 0, 0);
      }
    }

    // ---- online softmax
    float ps[4][8];
    float scl[4];
    #pragma unroll
    for (int e = 0; e < 4; ++e) {
      const int qg = q0 + wid * 16 + g4 * 4 + e;
      float s[8];
      float mx = mrun[e];
      #pragma unroll
      for (int f = 0; f < 8; ++f) {
        const int kg = k0 + 16 * f + l15;
        const float sv = __uint_as_float((unsigned)se[e][f] << 16);
        const float t = (aqk[f][e] + sv) * 0.125f;
        s[f] = (kg <= qg) ? t : -1e30f;
        mx = fmaxf(mx, s[f]);
      }
      #pragma unroll
      for (int o = 1; o < 16; o <<= 1) mx = fmaxf(mx, __shfl_xor(mx, o));
      const float sc_ = __expf(mrun[e] - mx);
      float ls = 0.f;
      #pragma unroll
      for (int f = 0; f < 8; ++f) { const float p = __expf(s[f] - mx); ps[e][f] = p; ls += p; }
      #pragma unroll
      for (int o = 1; o < 16; o <<= 1) ls += __shfl_xor(ls, o);
      lrun[e] = lrun[e] * sc_ + ls;
      mrun[e] = mx;
      scl[e] = sc_;
    }
    #pragma unroll
    for (int fd = 0; fd < 4; ++fd)
      #pragma unroll
      for (int e = 0; e < 4; ++e) apv[fd][e] *= scl[e];

    // P -> LDS (wave-private rows), then PV
    #pragma unroll
    for (int e = 0; e < 4; ++e) {
      char* pr = Plds + (wid * 16 + g4 * 4 + e) * 272 + l15 * 2;
      #pragma unroll
      for (int f = 0; f < 8; ++f)
        *(bf16*)(pr + f * 32) = __float2bfloat16(ps[e][f]);
    }
    asm volatile("s_waitcnt lgkmcnt(0)" ::: "memory");
    __builtin_amdgcn_sched_barrier(0);

    #pragma unroll
    for (int ks = 0; ks < 4; ++ks) {
      const int ko = (ks * 32 + g4 * 8) * 2;
      bf16x8 a = *(const bf16x8*)(Plds + (wid * 16 + l15) * 272 + ko);
      #pragma unroll
      for (int fd = 0; fd < 4; ++fd) {
        bf16x8 bb = *(const bf16x8*)(Vlds + (((16 * fd + l15) * 256 + ko) ^ xk));
        apv[fd] = __builtin_amdgcn_mfma_f32_16x16x32_bf16(a, bb, apv[fd], 0, 0, 0);
      }
    }
  }

  #pragma unroll
  for (int e = 0; e < 4; ++e) {
    const float rl = 1.f / lrun[e];
    const int qg = q0 + wid * 16 + g4 * 4 + e;
    bf16* orow = ob + ((long)b * NS + qg) * ND + h * 64;
    #pragma unroll
    for (int fd = 0; fd < 4; ++fd)
      orow[16 * fd + l15] = __float2bfloat16(apv[fd][e] * rl);
  }
}

// ------ vectorized transpose+convert: in f32 (R x C) -> out bf16 (C x R) ------
__global__ void transpose64_k(const float* __restrict__ in, bf16* __restrict__ out,
                              int R, int C, long inZ, long outZ) {
  __shared__ float t[64][65];
  const float* ip = in + (long)blockIdx.z * inZ;
  bf16* op = out + (long)blockIdx.z * outZ;
  const int c0 = blockIdx.x * 64, r0 = blockIdx.y * 64;
  const int tid = threadIdx.x;
  const int lr = tid >> 4;
  const int lc = (tid & 15) * 4;
  #pragma unroll
  for (int i = 0; i < 4; ++i) {
    const float4 v = *(const float4*)(ip + (long)(r0 + lr + 16 * i) * C + c0 + lc);
    t[lr + 16 * i][lc]     = v.x;
    t[lr + 16 * i][lc + 1] = v.y;
    t[lr + 16 * i][lc + 2] = v.z;
    t[lr + 16 * i][lc + 3] = v.w;
  }
  __syncthreads();
  #pragma unroll
  for (int i = 0; i < 4; ++i) {
    const int oc = lr + 16 * i;
    ushort4 u;
    bf16 h0 = __float2bfloat16(t[lc][oc]);
    bf16 h1 = __float2bfloat16(t[lc + 1][oc]);
    bf16 h2 = __float2bfloat16(t[lc + 2][oc]);
    bf16 h3 = __float2bfloat16(t[lc + 3][oc]);
    u.x = *(unsigned short*)&h0; u.y = *(unsigned short*)&h1;
    u.z = *(unsigned short*)&h2; u.w = *(unsigned short*)&h3;
    *(ushort4*)(op + (long)(c0 + oc) * R + r0 + lc) = u;
  }
}

// v (B,S,D) -> vt (B,H,Dh,S)
__global__ void transpose_v_k(const bf16* __restrict__ v, bf16* __restrict__ vt) {
  __shared__ bf16 t[32][33];
  const int z = blockIdx.z, b = z >> 4, h = z & 15;
  const bf16* ip = v + (long)b * NS * ND + h * 64;
  bf16* op = vt + (long)z * 64 * NS;
  const int s0 = blockIdx.x * 32, d0 = blockIdx.y * 32;
  const int tx = threadIdx.x, ty = threadIdx.y;
  #pragma unroll
  for (int i = 0; i < 4; ++i)
    t[ty * 4 + i][tx] = ip[(long)(s0 + ty * 4 + i) * ND + d0 + tx];
  __syncthreads();
  #pragma unroll
  for (int i = 0; i < 4; ++i)
    op[(long)(d0 + ty * 4 + i) * NS + s0 + tx] = t[tx][ty * 4 + i];
}

__global__ void cvt_bf16_k(const float* __restrict__ in, bf16* __restrict__ out, int n) {
  int i = blockIdx.x * 256 + threadIdx.x;
  if (i < n) out[i] = __float2bfloat16(in[i]);
}

__global__ void pack3_k(const float* __restrict__ a, const float* __restrict__ b,
                        const float* __restrict__ c, float* __restrict__ out) {
  int i = blockIdx.x * 256 + threadIdx.x;
  if (i >= NL * 3 * ND) return;
  int d = i % ND, r = (i / ND) % 3, l = i / (3 * ND);
  const float* src = (r == 0) ? a : ((r == 1) ? b : c);
  out[i] = src[l * ND + d];
}

__global__ void embed_k(const int* __restrict__ tok, const float* __restrict__ emb,
                        float* __restrict__ x, bf16* __restrict__ xb) {
  const int row = blockIdx.x;
  const int t = tok[row];
  const float4 val = ((const float4*)(emb + (long)t * ND))[threadIdx.x];
  ((float4*)(x + (long)row * ND))[threadIdx.x] = val;
  bf16* xp = xb + (long)row * ND + threadIdx.x * 4;
  xp[0] = __float2bfloat16(val.x); xp[1] = __float2bfloat16(val.y);
  xp[2] = __float2bfloat16(val.z); xp[3] = __float2bfloat16(val.w);
}

// x = LN(x + g0+g1+g2+g3) * s + b (in place on x), also emit xb = bf16(x)
__global__ void resid_ln_k(float* __restrict__ x, const float* __restrict__ g,
                           long gs,
                           const float* __restrict__ s, const float* __restrict__ b,
                           bf16* __restrict__ xb) {
  const int row = blockIdx.x, tid = threadIdx.x;
  const float4 xv = ((const float4*)(x + (long)row * ND))[tid];
  const float4 ga = ((const float4*)(g + (long)row * ND))[tid];
  const float4 gb = ((const float4*)(g + gs + (long)row * ND))[tid];
  const float4 gc = ((const float4*)(g + 2 * gs + (long)row * ND))[tid];
  const float4 gd = ((const float4*)(g + 3 * gs + (long)row * ND))[tid];
  float h0 = xv.x + ga.x + gb.x + gc.x + gd.x;
  float h1 = xv.y + ga.y + gb.y + gc.y + gd.y;
  float h2 = xv.z + ga.z + gb.z + gc.z + gd.z;
  float h3 = xv.w + ga.w + gb.w + gc.w + gd.w;
  float ls = h0 + h1 + h2 + h3;
  __shared__ float red[8];
  #pragma unroll
  for (int o = 32; o; o >>= 1) ls += __shfl_xor(ls, o);
  const int lane = tid & 63, wid = tid >> 6;
  if (lane == 0) red[wid] = ls;
  __syncthreads();
  const float mu = (red[0] + red[1] + red[2] + red[3]) * (1.f / ND);
  const float d0 = h0 - mu, d1 = h1 - mu, d2 = h2 - mu, d3 = h3 - mu;
  float lv = d0 * d0 + d1 * d1 + d2 * d2 + d3 * d3;
  #pragma unroll
  for (int o = 32; o; o >>= 1) lv += __shfl_xor(lv, o);
  if (lane == 0) red[4 + wid] = lv;
  __syncthreads();
  const float rs = rsqrtf((red[4] + red[5] + red[6] + red[7]) * (1.f / ND) + 1e-5f);
  const float4 sv = ((const float4*)s)[tid];
  const float4 bv = ((const float4*)b)[tid];
  const float y0 = d0 * rs * sv.x + bv.x, y1 = d1 * rs * sv.y + bv.y;
  const float y2 = d2 * rs * sv.z + bv.z, y3 = d3 * rs * sv.w + bv.w;
  ((float4*)(x + (long)row * ND))[tid] = make_float4(y0, y1, y2, y3);
  bf16* xp = xb + (long)row * ND + tid * 4;
  xp[0] = __float2bfloat16(y0); xp[1] = __float2bfloat16(y1);
  xp[2] = __float2bfloat16(y2); xp[3] = __float2bfloat16(y3);
}

extern "C" void kernel_launch(void* const* d_in, const int* in_sizes, int n_in,
                              void* d_out, int out_size, void* d_ws, size_t ws_size,
                              hipStream_t stream) {
  const int*   tokens = (const int*)d_in[0];
  const float* emb  = (const float*)d_in[1];
  const float* Wq   = (const float*)d_in[2];
  const float* bq   = (const float*)d_in[3];
  const float* Wk   = (const float*)d_in[4];
  const float* bk   = (const float*)d_in[5];
  const float* Wv   = (const float*)d_in[6];
  const float* bv   = (const float*)d_in[7];
  const float* Wo   = (const float*)d_in[8];
  const float* bo   = (const float*)d_in[9];
  const float* rpe  = (const float*)d_in[10];
  const float* ln1s = (const float*)d_in[11];
  const float* ln1b = (const float*)d_in[12];
  const float* ln2s = (const float*)d_in[13];
  const float* ln2b = (const float*)d_in[14];
  const float* W1   = (const float*)d_in[15];
  const float* b1   = (const float*)d_in[16];
  const float* W2   = (const float*)d_in[17];
  const float* b2   = (const float*)d_in[18];
  const float* Wout = (const float*)d_in[19];
  const float* bout = (const float*)d_in[20];
  float* out = (float*)d_out;

  char* wsb = (char*)d_ws;
  size_t off = 0;
  auto take = [&](size_t bytes) -> void* {
    void* r = wsb + off;
    off = (off + bytes + 255) & ~(size_t)255;
    return r;
  };
  bf16*  wqkvT = (bf16*)take((size_t)NL * 3 * ND * ND * 2);
  bf16*  woT   = (bf16*)take((size_t)NL * ND * ND * 2);
  bf16*  w1T   = (bf16*)take((size_t)NL * NF * ND * 2);
  bf16*  w2T   = (bf16*)take((size_t)NL * ND * NF * 2);
  bf16*  woutT = (bf16*)take((size_t)NV * ND * 2);
  bf16*  rpeb  = (bf16*)take((size_t)NL * NS * NDH * 2);
  float* qkvb  = (float*)take((size_t)NL * 3 * ND * 4);
  float* x     = (float*)take((size_t)NB * NS * ND * 4);
  bf16*  xb    = (bf16*)take((size_t)NB * NS * ND * 2);
  bf16*  qkv   = (bf16*)take((size_t)3 * NB * NS * ND * 2);
  bf16*  vt    = (bf16*)take((size_t)NB * NS * ND * 2);
  bf16*  ob    = (bf16*)take((size_t)NB * NS * ND * 2);
  float* g     = (float*)take((size_t)4 * NB * NS * ND * 4);
  bf16*  hbuf  = (bf16*)take((size_t)NB * NS * NF * 2);
  bf16*  qe    = (bf16*)take((size_t)NB * NH * NS * NS * 2 + 4096);
  (void)in_sizes; (void)n_in; (void)out_size; (void)ws_size;

  const long gStride = (long)NB * NS * ND;

  transpose64_k<<<dim3(ND/64, ND/64, NL), 256, 0, stream>>>(Wq, wqkvT,                   ND, ND, (long)ND*ND, (long)3*ND*ND);
  transpose64_k<<<dim3(ND/64, ND/64, NL), 256, 0, stream>>>(Wk, wqkvT + (size_t)ND*ND,   ND, ND, (long)ND*ND, (long)3*ND*ND);
  transpose64_k<<<dim3(ND/64, ND/64, NL), 256, 0, stream>>>(Wv, wqkvT + (size_t)2*ND*ND, ND, ND, (long)ND*ND, (long)3*ND*ND);
  transpose64_k<<<dim3(ND/64, ND/64, NL), 256, 0, stream>>>(Wo, woT,                     ND, ND, (long)ND*ND, (long)ND*ND);
  transpose64_k<<<dim3(NF/64, ND/64, NL), 256, 0, stream>>>(W1, w1T,                     ND, NF, (long)ND*NF, (long)NF*ND);
  transpose64_k<<<dim3(ND/64, NF/64, NL), 256, 0, stream>>>(W2, w2T,                     NF, ND, (long)NF*ND, (long)ND*NF);
  transpose64_k<<<dim3(NV/64, ND/64, 1),  256, 0, stream>>>(Wout, woutT,                 ND, NV, 0, 0);
  cvt_bf16_k<<<(NL*NS*NDH + 255)/256, 256, 0, stream>>>(rpe, rpeb, NL*NS*NDH);
  pack3_k<<<(NL*3*ND + 255)/256, 256, 0, stream>>>(bq, bk, bv, qkvb);
  embed_k<<<NB*NS, 256, 0, stream>>>(tokens, emb, x, xb);

  const dim3 tb(32, 8);
  for (int l = 0; l < NL; ++l) {
    // QKV fused (N=3072), slab-scatter epilogue
    gemm128_bt<3, true, 1><<<dim3(3*ND/256, NB*NS/128), 256, 0, stream>>>(
        xb, wqkvT + (size_t)l*3*ND*ND, qkv, qkvb + (size_t)l*3*ND,
        ND, ND, ND, ND, gStride);
    transpose_v_k<<<dim3(NS/32, 2, NB*NH), tb, 0, stream>>>(qkv + (size_t)2*NB*NS*ND, vt);
    // Q @ E^T -> qe[z][q][m] (bf16, m-space; only live band written)
    gemm_bt<128, 1, 3, false, 0, 0><<<dim3(NS/128, NS/128, NB*NH), 256, 0, stream>>>(
        qkv, rpeb + (size_t)l*NS*NDH, qe, nullptr,
        NS, NS, NDH, ND, NDH, NS, NH,
        (long)NS*ND, 64, 0, 0, (long)NH*NS*NS, (long)NS*NS, 0);
    flash_attn_k<<<dim3(NB*NH, 16), 256, 0, stream>>>(qkv, vt, qe, ob);
    // O projection, split-K x4 -> g0..g3 (f32; bias on z==0); 256 blocks
    gemm128_bt<0, true, 4><<<dim3(ND/256, NB*NS/128, 4), 256, 0, stream>>>(
        ob, woT + (size_t)l*ND*ND, g, bo + (size_t)l*ND, ND, ND, ND, ND, gStride);
    resid_ln_k<<<NB*NS, 256, 0, stream>>>(x, g, gStride,
        ln1s + (size_t)l*ND, ln1b + (size_t)l*ND, xb);
    // FFN1, bias + GELU, bf16 out (256 blocks)
    gemm128_bt<2, true, 1><<<dim3(NF/256, NB*NS/128), 256, 0, stream>>>(
        xb, w1T + (size_t)l*NF*ND, hbuf, b1 + (size_t)l*NF, ND, ND, ND, NF, 0);
    // FFN2, split-K x4 (K=4096 -> 4x1024) -> g0..g3; 256 blocks
    gemm128_bt<0, true, 4><<<dim3(ND/256, NB*NS/128, 4), 256, 0, stream>>>(
        hbuf, w2T + (size_t)l*ND*NF, g, b2 + (size_t)l*ND, NF, NF, NF, ND, gStride);
    resid_ln_k<<<NB*NS, 256, 0, stream>>>(x, g, gStride,
        ln2s + (size_t)l*ND, ln2b + (size_t)l*ND, xb);
  }
  // final vocab projection: pair-pipelined 256x256 kernel (1000 blocks)
  gemm256p<0, true><<<dim3(NV/256, NB*NS/256), 512, 0, stream>>>(
      xb, woutT, out, bout, ND, ND, ND, NV);
}